// Round 1
// baseline (717.221 us; speedup 1.0000x reference)
//
#include <hip/hip_runtime.h>
#include <math.h>

#define DIM 128
#define HEADS 8
#define HD 16

__device__ __forceinline__ float lrelu(float x, float s) { return x >= 0.f ? x : s * x; }

// ---------------- CSR build (group edges by destination) ----------------
__global__ void k_hist(const int* __restrict__ ei, int E, int N, int* __restrict__ cnt) {
  int tot = E + N;
  for (int i = blockIdx.x * blockDim.x + threadIdx.x; i < tot; i += gridDim.x * blockDim.x) {
    int d = (i < E) ? ei[E + i] : (i - E);  // self-loops appended
    atomicAdd(&cnt[d], 1);
  }
}

__global__ __launch_bounds__(1024) void k_scan(const int* __restrict__ cnt, int n,
                                               int* __restrict__ rowptr, int* __restrict__ cursor) {
  __shared__ int wsum[16];
  __shared__ int sbase;
  int tid = threadIdx.x, lane = tid & 63, wv = tid >> 6;
  if (tid == 0) sbase = 0;
  __syncthreads();
  for (int start = 0; start < n; start += 1024) {
    int i = start + tid;
    int v = (i < n) ? cnt[i] : 0;
    int s = v;
#pragma unroll
    for (int off = 1; off < 64; off <<= 1) {
      int t = __shfl_up(s, off, 64);
      if (lane >= off) s += t;
    }
    if (lane == 63) wsum[wv] = s;
    __syncthreads();
    int base = sbase;
    int woff = 0;
#pragma unroll
    for (int wI = 0; wI < 16; ++wI) woff += (wI < wv) ? wsum[wI] : 0;
    if (i < n) { int e = base + woff + s - v; rowptr[i] = e; cursor[i] = e; }
    __syncthreads();
    if (tid == 1023) sbase = base + woff + s;
    __syncthreads();
  }
  if (tid == 0) rowptr[n] = sbase;
}

__global__ void k_scatter(const int* __restrict__ ei, int E, int N,
                          int* __restrict__ cursor, int* __restrict__ colb) {
  int tot = E + N;
  for (int i = blockIdx.x * blockDim.x + threadIdx.x; i < tot; i += gridDim.x * blockDim.x) {
    int s, d;
    if (i < E) { s = ei[i]; d = ei[E + i]; } else { s = i - E; d = s; }
    int pos = atomicAdd(&cursor[d], 1);
    colb[pos] = s;
  }
}

// ---------------- xh = x @ W, plus per-head alpha_src/alpha_dst ----------------
// 256 threads, 16 nodes per block. W staged in LDS (64KB).
__global__ __launch_bounds__(256) void k_linear(const float* __restrict__ x, const float* __restrict__ W,
                                                const float* __restrict__ avs, const float* __restrict__ avd,
                                                float* __restrict__ xh, float* __restrict__ asrc,
                                                float* __restrict__ adst, int N) {
  __shared__ float sW[DIM * DIM];
  int tid = threadIdx.x;
#pragma unroll
  for (int i = 0; i < (DIM * DIM) / 256; ++i) sW[i * 256 + tid] = W[i * 256 + tid];
  __syncthreads();
  int d = tid & 127, half = tid >> 7;
  int h = d >> 4, j = d & 15;
  float cs = avs[h * HD + j], cd = avd[h * HD + j];
  int n0 = blockIdx.x * 16 + half * 8;
  for (int g = 0; g < 2; ++g) {
    int nb = n0 + g * 4;
    if (nb + 3 >= N && nb >= N) break;
    const float* x0 = x + (size_t)nb * DIM;
    const float* x1 = x0 + DIM;
    const float* x2 = x0 + 2 * DIM;
    const float* x3 = x0 + 3 * DIM;
    float a0 = 0.f, a1 = 0.f, a2 = 0.f, a3 = 0.f;
#pragma unroll 4
    for (int k = 0; k < DIM; ++k) {
      float w = sW[k * DIM + d];
      a0 = fmaf(x0[k], w, a0);
      a1 = fmaf(x1[k], w, a1);
      a2 = fmaf(x2[k], w, a2);
      a3 = fmaf(x3[k], w, a3);
    }
    xh[(size_t)(nb + 0) * DIM + d] = a0;
    xh[(size_t)(nb + 1) * DIM + d] = a1;
    xh[(size_t)(nb + 2) * DIM + d] = a2;
    xh[(size_t)(nb + 3) * DIM + d] = a3;
    float s0 = a0 * cs, s1 = a1 * cs, s2 = a2 * cs, s3 = a3 * cs;
    float t0 = a0 * cd, t1 = a1 * cd, t2 = a2 * cd, t3 = a3 * cd;
#pragma unroll
    for (int off = 1; off < 16; off <<= 1) {
      s0 += __shfl_xor(s0, off, 64); s1 += __shfl_xor(s1, off, 64);
      s2 += __shfl_xor(s2, off, 64); s3 += __shfl_xor(s3, off, 64);
      t0 += __shfl_xor(t0, off, 64); t1 += __shfl_xor(t1, off, 64);
      t2 += __shfl_xor(t2, off, 64); t3 += __shfl_xor(t3, off, 64);
    }
    if (j == 0) {
      asrc[(nb + 0) * HEADS + h] = s0; asrc[(nb + 1) * HEADS + h] = s1;
      asrc[(nb + 2) * HEADS + h] = s2; asrc[(nb + 3) * HEADS + h] = s3;
      adst[(nb + 0) * HEADS + h] = t0; adst[(nb + 1) * HEADS + h] = t1;
      adst[(nb + 2) * HEADS + h] = t2; adst[(nb + 3) * HEADS + h] = t3;
    }
  }
}

// ---------------- GAT aggregation: one wave per destination node ----------------
__global__ __launch_bounds__(256) void k_gat_agg(const int* __restrict__ rowptr, const int* __restrict__ colb,
                                                 const float* __restrict__ xh, const float* __restrict__ asrc,
                                                 const float* __restrict__ adst, const float* __restrict__ bias,
                                                 float* __restrict__ hout, int N) {
  __shared__ float sm[4][8], sd[4][8];
  int tid = threadIdx.x, lane = tid & 63, wv = tid >> 6;
  int n = blockIdx.x * 4 + wv;
  int base = 0, deg = 0;
  if (n < N) { base = rowptr[n]; deg = rowptr[n + 1] - base; }
  int ha = lane & 7;
  float adst_a = (n < N) ? adst[n * HEADS + ha] : 0.f;
  // pass A1: per-head max over incoming edges
  float m = -INFINITY;
  for (int i = lane >> 3; i < deg; i += 8) {
    int c = colb[base + i];
    float e = lrelu(asrc[c * HEADS + ha] + adst_a, 0.2f);
    m = fmaxf(m, e);
  }
#pragma unroll
  for (int off = 8; off < 64; off <<= 1) m = fmaxf(m, __shfl_xor(m, off, 64));
  // pass A2: per-head sum of exp
  float ssum = 0.f;
  for (int i = lane >> 3; i < deg; i += 8) {
    int c = colb[base + i];
    float e = lrelu(asrc[c * HEADS + ha] + adst_a, 0.2f);
    ssum += expf(e - m);
  }
#pragma unroll
  for (int off = 8; off < 64; off <<= 1) ssum += __shfl_xor(ssum, off, 64);
  if (lane < 8) { sm[wv][lane] = m; sd[wv][lane] = ssum + 1e-16f; }
  __syncthreads();
  if (n >= N) return;
  // pass B: weighted gather of xh[src]
  int d0 = lane, d1 = lane + 64;
  int h0 = lane >> 4, h1 = h0 + 4;
  float m0 = sm[wv][h0], m1 = sm[wv][h1];
  float r0 = 1.f / sd[wv][h0], r1 = 1.f / sd[wv][h1];
  float ad0 = adst[n * HEADS + h0], ad1 = adst[n * HEADS + h1];
  float acc0 = 0.f, acc1 = 0.f;
  for (int i = 0; i < deg; ++i) {
    int c = colb[base + i];
    const float* xr = xh + (size_t)c * DIM;
    float e0 = lrelu(asrc[c * HEADS + h0] + ad0, 0.2f);
    float e1 = lrelu(asrc[c * HEADS + h1] + ad1, 0.2f);
    float w0 = expf(e0 - m0) * r0;
    float w1 = expf(e1 - m1) * r1;
    acc0 = fmaf(w0, xr[d0], acc0);
    acc1 = fmaf(w1, xr[d1], acc1);
  }
  hout[(size_t)n * DIM + d0] = lrelu(acc0 + bias[d0], 0.01f);
  hout[(size_t)n * DIM + d1] = lrelu(acc1 + bias[d1], 0.01f);
}

// ---------------- score MLP: one wave per node ----------------
__global__ __launch_bounds__(256) void k_score(const float* __restrict__ h2,
                                               const float* __restrict__ wm1, const float* __restrict__ bm1,
                                               const float* __restrict__ wm2, const float* __restrict__ bm2,
                                               float* __restrict__ scores, int N) {
  __shared__ float sw[DIM * 64];
  int tid = threadIdx.x;
  for (int i = tid; i < DIM * 64; i += 256) sw[i] = wm1[i];
  __syncthreads();
  int lane = tid & 63, wv = tid >> 6;
  float b1v = bm1[lane], w2v = wm2[lane], b2v = bm2[0];
  for (int n = blockIdx.x * 4 + wv; n < N; n += gridDim.x * 4) {
    const float* hr = h2 + (size_t)n * DIM;
    float acc = 0.f;
#pragma unroll 4
    for (int k = 0; k < DIM; ++k) acc = fmaf(hr[k], sw[k * 64 + lane], acc);
    float p = lrelu(acc + b1v, 0.01f) * w2v;
#pragma unroll
    for (int off = 32; off; off >>= 1) p += __shfl_xor(p, off, 64);
    if (lane == 0) scores[n] = p + b2v;
  }
}

// ---------------- global softmax + weighted aggregation ----------------
__global__ __launch_bounds__(256) void k_pmax(const float* __restrict__ sc, int N, float* __restrict__ pmax) {
  __shared__ float red[256];
  int tid = threadIdx.x;
  float m = -INFINITY;
  for (int i = blockIdx.x * 256 + tid; i < N; i += 256 * gridDim.x) m = fmaxf(m, sc[i]);
  red[tid] = m; __syncthreads();
  for (int st = 128; st > 0; st >>= 1) { if (tid < st) red[tid] = fmaxf(red[tid], red[tid + st]); __syncthreads(); }
  if (tid == 0) pmax[blockIdx.x] = red[0];
}

__global__ __launch_bounds__(256) void k_gmax(const float* __restrict__ p, int n, float* __restrict__ g) {
  __shared__ float red[256];
  int tid = threadIdx.x;
  red[tid] = (tid < n) ? p[tid] : -INFINITY; __syncthreads();
  for (int st = 128; st > 0; st >>= 1) { if (tid < st) red[tid] = fmaxf(red[tid], red[tid + st]); __syncthreads(); }
  if (tid == 0) g[0] = red[0];
}

__global__ __launch_bounds__(256) void k_expsum(const float* __restrict__ sc, int N, const float* __restrict__ gM,
                                                float* __restrict__ wun, float* __restrict__ psum) {
  __shared__ float red[256];
  int tid = threadIdx.x;
  float M = gM[0];
  float s = 0.f;
  for (int i = blockIdx.x * 256 + tid; i < N; i += 256 * gridDim.x) {
    float e = expf(sc[i] - M);
    wun[i] = e;
    s += e;
  }
  red[tid] = s; __syncthreads();
  for (int st = 128; st > 0; st >>= 1) { if (tid < st) red[tid] += red[tid + st]; __syncthreads(); }
  if (tid == 0) psum[blockIdx.x] = red[0];
}

__global__ __launch_bounds__(256) void k_gsum(const float* __restrict__ p, int n, float* __restrict__ g) {
  __shared__ float red[256];
  int tid = threadIdx.x;
  red[tid] = (tid < n) ? p[tid] : 0.f; __syncthreads();
  for (int st = 128; st > 0; st >>= 1) { if (tid < st) red[tid] += red[tid + st]; __syncthreads(); }
  if (tid == 0) g[0] = red[0];
}

__global__ __launch_bounds__(128) void k_wagg(const float* __restrict__ wun, const float* __restrict__ h2,
                                              int N, float* __restrict__ agg) {
  int d = threadIdx.x;
  float acc = 0.f;
  for (int n = blockIdx.x; n < N; n += gridDim.x) acc += wun[n] * h2[(size_t)n * DIM + d];
  atomicAdd(&agg[d], acc);
}

// ---------------- final MLP + layernorm (single block, 128 threads) ----------------
__global__ __launch_bounds__(128) void k_final(const float* __restrict__ agg, const float* __restrict__ gZ,
                                               const float* __restrict__ wa1, const float* __restrict__ ba1,
                                               const float* __restrict__ wa2, const float* __restrict__ ba2,
                                               const float* __restrict__ gamma, const float* __restrict__ beta,
                                               float* __restrict__ out) {
  __shared__ float sa[128], sh[64], red[128];
  int t = threadIdx.x;
  float Z = gZ[0];
  sa[t] = agg[t] / Z;
  __syncthreads();
  if (t < 64) {
    float a = 0.f;
    for (int k = 0; k < 128; ++k) a = fmaf(sa[k], wa1[k * 64 + t], a);
    a += ba1[t];
    sh[t] = lrelu(a, 0.01f);
  }
  __syncthreads();
  float z = ba2[t];
  for (int j = 0; j < 64; ++j) z = fmaf(sh[j], wa2[j * 128 + t], z);
  red[t] = z; __syncthreads();
  for (int st = 64; st > 0; st >>= 1) { if (t < st) red[t] += red[t + st]; __syncthreads(); }
  float mu = red[0] / 128.f;
  __syncthreads();
  red[t] = (z - mu) * (z - mu); __syncthreads();
  for (int st = 64; st > 0; st >>= 1) { if (t < st) red[t] += red[t + st]; __syncthreads(); }
  float var = red[0] / 128.f;
  out[t] = gamma[t] * (z - mu) / sqrtf(var + 1e-5f) + beta[t];
}

extern "C" void kernel_launch(void* const* d_in, const int* in_sizes, int n_in,
                              void* d_out, int out_size, void* d_ws, size_t ws_size,
                              hipStream_t stream) {
  const float* feat = (const float*)d_in[0];
  const int* ei = (const int*)d_in[1];
  const float* W1 = (const float*)d_in[2];
  const float* as1 = (const float*)d_in[3];
  const float* ad1 = (const float*)d_in[4];
  const float* b1 = (const float*)d_in[5];
  const float* W2 = (const float*)d_in[6];
  const float* as2 = (const float*)d_in[7];
  const float* ad2 = (const float*)d_in[8];
  const float* b2 = (const float*)d_in[9];
  const float* wm1 = (const float*)d_in[10];
  const float* bm1 = (const float*)d_in[11];
  const float* wm2 = (const float*)d_in[12];
  const float* bm2 = (const float*)d_in[13];
  const float* wa1 = (const float*)d_in[14];
  const float* ba1 = (const float*)d_in[15];
  const float* wa2 = (const float*)d_in[16];
  const float* ba2 = (const float*)d_in[17];
  const float* gamma = (const float*)d_in[18];
  const float* beta = (const float*)d_in[19];
  float* out = (float*)d_out;

  int N = in_sizes[0] / DIM;   // 50000
  int E = in_sizes[1] / 2;     // 600000

  char* ws = (char*)d_ws;
  size_t off = 0;
  auto alloc = [&](size_t bytes) -> void* {
    void* p = ws + off;
    off = (off + bytes + 255) & ~(size_t)255;
    return p;
  };
  int* cnt = (int*)alloc((size_t)N * 4);
  int* rowptr = (int*)alloc((size_t)(N + 1) * 4);
  int* cursor = (int*)alloc((size_t)N * 4);
  int* colb = (int*)alloc((size_t)(E + N) * 4);
  float* xh = (float*)alloc((size_t)N * DIM * 4);
  float* h1 = (float*)alloc((size_t)N * DIM * 4);
  float* h2 = (float*)alloc((size_t)N * DIM * 4);
  float* asrcb = (float*)alloc((size_t)N * HEADS * 4);
  float* adstb = (float*)alloc((size_t)N * HEADS * 4);
  float* scores = (float*)alloc((size_t)N * 4);
  float* wun = (float*)alloc((size_t)N * 4);
  float* pmax = (float*)alloc(256 * 4);
  float* psum = (float*)alloc(256 * 4);
  float* gM = (float*)alloc(4);
  float* gZ = (float*)alloc(4);
  float* agg = (float*)alloc(DIM * 4);

  hipMemsetAsync(cnt, 0, (size_t)N * 4, stream);
  hipMemsetAsync(agg, 0, DIM * 4, stream);

  k_hist<<<1024, 256, 0, stream>>>(ei, E, N, cnt);
  k_scan<<<1, 1024, 0, stream>>>(cnt, N, rowptr, cursor);
  k_scatter<<<1024, 256, 0, stream>>>(ei, E, N, cursor, colb);

  int gl = (N + 15) / 16;
  int ga = (N + 3) / 4;
  k_linear<<<gl, 256, 0, stream>>>(feat, W1, as1, ad1, xh, asrcb, adstb, N);
  k_gat_agg<<<ga, 256, 0, stream>>>(rowptr, colb, xh, asrcb, adstb, b1, h1, N);
  k_linear<<<gl, 256, 0, stream>>>(h1, W2, as2, ad2, xh, asrcb, adstb, N);
  k_gat_agg<<<ga, 256, 0, stream>>>(rowptr, colb, xh, asrcb, adstb, b2, h2, N);

  k_score<<<2048, 256, 0, stream>>>(h2, wm1, bm1, wm2, bm2, scores, N);
  k_pmax<<<256, 256, 0, stream>>>(scores, N, pmax);
  k_gmax<<<1, 256, 0, stream>>>(pmax, 256, gM);
  k_expsum<<<256, 256, 0, stream>>>(scores, N, gM, wun, psum);
  k_gsum<<<1, 256, 0, stream>>>(psum, 256, gZ);
  k_wagg<<<256, 128, 0, stream>>>(wun, h2, N, agg);
  k_final<<<1, 128, 0, stream>>>(agg, gZ, wa1, ba1, wa2, ba2, gamma, beta, out);
}

// Round 2
// 541.969 us; speedup vs baseline: 1.3234x; 1.3234x over previous
//
#include <hip/hip_runtime.h>
#include <math.h>

#define DIM 128
#define HEADS 8
#define HD 16

typedef __attribute__((ext_vector_type(8))) short s16x8;
typedef __attribute__((ext_vector_type(4))) float f32x4;

__device__ __forceinline__ float lrelu(float x, float s) { return x >= 0.f ? x : s * x; }

__device__ __forceinline__ unsigned short f2bf(float x) {
  unsigned u = __float_as_uint(x);
  return (unsigned short)((u + 0x7FFFu + ((u >> 16) & 1u)) >> 16);
}
__device__ __forceinline__ float bf2f(unsigned short b) {
  return __uint_as_float(((unsigned)b) << 16);
}

// ---------------- CSR build (group edges by destination) ----------------
__global__ void k_hist(const int* __restrict__ ei, int E, int N, int* __restrict__ cnt) {
  int tot = E + N;
  for (int i = blockIdx.x * blockDim.x + threadIdx.x; i < tot; i += gridDim.x * blockDim.x) {
    int d = (i < E) ? ei[E + i] : (i - E);  // self-loops appended
    atomicAdd(&cnt[d], 1);
  }
}

// parallel scan: per-block scan -> top scan -> fixup.  excl aliases `cursor`.
__global__ __launch_bounds__(256) void k_scan_blk(const int* __restrict__ cnt, int n,
                                                  int* __restrict__ excl, int* __restrict__ bsum) {
  __shared__ int wsum[4];
  int tid = threadIdx.x, l = tid & 63, w = tid >> 6;
  int i = blockIdx.x * 256 + tid;
  int v = (i < n) ? cnt[i] : 0;
  int s = v;
#pragma unroll
  for (int off = 1; off < 64; off <<= 1) {
    int t = __shfl_up(s, off, 64);
    if (l >= off) s += t;
  }
  if (l == 63) wsum[w] = s;
  __syncthreads();
  int add = 0;
#pragma unroll
  for (int k = 0; k < 4; ++k) add += (k < w) ? wsum[k] : 0;
  if (i < n) excl[i] = s + add - v;
  if (tid == 255) bsum[blockIdx.x] = s + add;
}

__global__ __launch_bounds__(256) void k_scan_top(const int* __restrict__ bsum, int nb,
                                                  int* __restrict__ boff, int* __restrict__ rowptrN) {
  __shared__ int wsum[4];
  int tid = threadIdx.x, l = tid & 63, w = tid >> 6;
  int v = (tid < nb) ? bsum[tid] : 0;
  int s = v;
#pragma unroll
  for (int off = 1; off < 64; off <<= 1) {
    int t = __shfl_up(s, off, 64);
    if (l >= off) s += t;
  }
  if (l == 63) wsum[w] = s;
  __syncthreads();
  int add = 0;
#pragma unroll
  for (int k = 0; k < 4; ++k) add += (k < w) ? wsum[k] : 0;
  if (tid < nb) boff[tid] = s + add - v;
  if (tid == 255) *rowptrN = s + add;
}

__global__ __launch_bounds__(256) void k_scan_fix(int* __restrict__ cursor, const int* __restrict__ boff,
                                                  int n, int* __restrict__ rowptr) {
  int i = blockIdx.x * 256 + threadIdx.x;
  if (i < n) {
    int r = boff[blockIdx.x] + cursor[i];
    rowptr[i] = r;
    cursor[i] = r;
  }
}

__global__ void k_scatter(const int* __restrict__ ei, int E, int N,
                          int* __restrict__ cursor, int* __restrict__ colb) {
  int tot = E + N;
  for (int i = blockIdx.x * blockDim.x + threadIdx.x; i < tot; i += gridDim.x * blockDim.x) {
    int s, d;
    if (i < E) { s = ei[i]; d = ei[E + i]; } else { s = i - E; d = s; }
    int pos = atomicAdd(&cursor[d], 1);
    colb[pos] = s;
  }
}

// ---------------- weight prep: W^T fragments (split bf16 hi/lo) + alpha-proj cols ----------------
// Frag layout is simply Wt[n][k] = W[k][n] as bf16 hi/lo; per-lane 8 contiguous k.
// Alpha cols: Ws[k][c] (c<8: src head c; c>=8: dst head c-8), stored transposed likewise.
__global__ __launch_bounds__(256) void k_wprep(const float* __restrict__ W,
                                               const float* __restrict__ av_s, const float* __restrict__ av_d,
                                               unsigned short* __restrict__ wh, unsigned short* __restrict__ wl,
                                               unsigned short* __restrict__ sh, unsigned short* __restrict__ sl) {
  int tid = threadIdx.x;
  for (int idx = tid; idx < DIM * DIM; idx += 256) {
    int n = idx >> 7, k = idx & 127;
    float v = W[k * DIM + n];
    unsigned short hb = f2bf(v);
    wh[idx] = hb;
    wl[idx] = f2bf(v - bf2f(hb));
  }
  for (int idx = tid; idx < 16 * DIM; idx += 256) {
    int n = idx >> 7, k = idx & 127;
    float acc = 0.f;
    if (n < 8) {
#pragma unroll
      for (int j = 0; j < 16; ++j) acc += W[k * DIM + n * 16 + j] * av_s[n * 16 + j];
    } else {
      int h = n - 8;
#pragma unroll
      for (int j = 0; j < 16; ++j) acc += W[k * DIM + h * 16 + j] * av_d[h * 16 + j];
    }
    unsigned short hb = f2bf(acc);
    sh[idx] = hb;
    sl[idx] = f2bf(acc - bf2f(hb));
  }
}

// ---------------- xh = x @ W via split-bf16 MFMA, alphas fused as extra col-tile ----------------
// 256 threads = 4 waves; wave w owns rows [blk*64 + w*16, +16); covers all 128 cols.
// mfma_f32_16x16x32_bf16: A: M=lane&15, K=(lane>>4)*8+j. B: N=lane&15, same K.
// D: col=lane&15, row=(lane>>4)*4+reg  [m89-verified].
__global__ __launch_bounds__(256) void k_linear_mfma(
    const float* __restrict__ x,
    const unsigned short* __restrict__ wh, const unsigned short* __restrict__ wl,
    const unsigned short* __restrict__ sh, const unsigned short* __restrict__ sl,
    float* __restrict__ xh, float* __restrict__ asrc, float* __restrict__ adst, int N) {
  int tid = threadIdx.x, l = tid & 63, w = tid >> 6;
  int g = l >> 4, c = l & 15;
  int rbase = blockIdx.x * 64 + w * 16;
  int row = rbase + c;
  int rc = min(row, N - 1);
  const float4* xf = (const float4*)(x + (size_t)rc * DIM);

  s16x8 Ah[4], Al[4];
#pragma unroll
  for (int kt = 0; kt < 4; ++kt) {
    float4 p = xf[kt * 8 + g * 2];
    float4 q = xf[kt * 8 + g * 2 + 1];
    s16x8 ah, al;
#define CV(v, j) { unsigned short hb = f2bf(v); ah[j] = (short)hb; al[j] = (short)f2bf((v) - bf2f(hb)); }
    CV(p.x, 0) CV(p.y, 1) CV(p.z, 2) CV(p.w, 3)
    CV(q.x, 4) CV(q.y, 5) CV(q.z, 6) CV(q.w, 7)
#undef CV
    Ah[kt] = ah;
    Al[kt] = al;
  }

  const s16x8* Bh = (const s16x8*)wh;
  const s16x8* Bl = (const s16x8*)wl;
#pragma unroll
  for (int ct = 0; ct < 8; ++ct) {
    f32x4 acc = {0.f, 0.f, 0.f, 0.f};
    int nb = (ct * 16 + c) * 4;
#pragma unroll
    for (int kt = 0; kt < 4; ++kt) {
      s16x8 bh = Bh[(nb + kt) * 4 + g];
      s16x8 bl = Bl[(nb + kt) * 4 + g];
      acc = __builtin_amdgcn_mfma_f32_16x16x32_bf16(Ah[kt], bh, acc, 0, 0, 0);
      acc = __builtin_amdgcn_mfma_f32_16x16x32_bf16(Ah[kt], bl, acc, 0, 0, 0);
      acc = __builtin_amdgcn_mfma_f32_16x16x32_bf16(Al[kt], bh, acc, 0, 0, 0);
    }
#pragma unroll
    for (int r = 0; r < 4; ++r) {
      int rr = rbase + g * 4 + r;
      if (rr < N) xh[(size_t)rr * DIM + ct * 16 + c] = acc[r];
    }
  }

  // alpha tile: cols 0..7 = alpha_src heads, 8..15 = alpha_dst heads
  const s16x8* Shp = (const s16x8*)sh;
  const s16x8* Slp = (const s16x8*)sl;
  f32x4 acc = {0.f, 0.f, 0.f, 0.f};
#pragma unroll
  for (int kt = 0; kt < 4; ++kt) {
    s16x8 bh = Shp[(c * 4 + kt) * 4 + g];
    s16x8 bl = Slp[(c * 4 + kt) * 4 + g];
    acc = __builtin_amdgcn_mfma_f32_16x16x32_bf16(Ah[kt], bh, acc, 0, 0, 0);
    acc = __builtin_amdgcn_mfma_f32_16x16x32_bf16(Ah[kt], bl, acc, 0, 0, 0);
    acc = __builtin_amdgcn_mfma_f32_16x16x32_bf16(Al[kt], bh, acc, 0, 0, 0);
  }
#pragma unroll
  for (int r = 0; r < 4; ++r) {
    int rr = rbase + g * 4 + r;
    if (rr < N) {
      if (c < 8) asrc[rr * HEADS + c] = acc[r];
      else adst[rr * HEADS + (c - 8)] = acc[r];
    }
  }
}

// ---------------- GAT aggregation: one wave per destination node ----------------
__global__ __launch_bounds__(256) void k_gat_agg(const int* __restrict__ rowptr, const int* __restrict__ colb,
                                                 const float* __restrict__ xh, const float* __restrict__ asrc,
                                                 const float* __restrict__ adst, const float* __restrict__ bias,
                                                 float* __restrict__ hout, int N) {
  __shared__ float sm[4][8], sd[4][8];
  int tid = threadIdx.x, lane = tid & 63, wv = tid >> 6;
  int n = blockIdx.x * 4 + wv;
  int base = 0, deg = 0;
  if (n < N) { base = rowptr[n]; deg = rowptr[n + 1] - base; }
  int ha = lane & 7;
  float adst_a = (n < N) ? adst[n * HEADS + ha] : 0.f;
  float m = -INFINITY;
  for (int i = lane >> 3; i < deg; i += 8) {
    int c = colb[base + i];
    float e = lrelu(asrc[c * HEADS + ha] + adst_a, 0.2f);
    m = fmaxf(m, e);
  }
#pragma unroll
  for (int off = 8; off < 64; off <<= 1) m = fmaxf(m, __shfl_xor(m, off, 64));
  float ssum = 0.f;
  for (int i = lane >> 3; i < deg; i += 8) {
    int c = colb[base + i];
    float e = lrelu(asrc[c * HEADS + ha] + adst_a, 0.2f);
    ssum += expf(e - m);
  }
#pragma unroll
  for (int off = 8; off < 64; off <<= 1) ssum += __shfl_xor(ssum, off, 64);
  if (lane < 8) { sm[wv][lane] = m; sd[wv][lane] = ssum + 1e-16f; }
  __syncthreads();
  if (n >= N) return;
  int d0 = lane, d1 = lane + 64;
  int h0 = lane >> 4, h1 = h0 + 4;
  float m0 = sm[wv][h0], m1 = sm[wv][h1];
  float r0 = 1.f / sd[wv][h0], r1 = 1.f / sd[wv][h1];
  float ad0 = adst[n * HEADS + h0], ad1 = adst[n * HEADS + h1];
  float acc0 = 0.f, acc1 = 0.f;
  for (int i = 0; i < deg; ++i) {
    int c = colb[base + i];
    const float* xr = xh + (size_t)c * DIM;
    float e0 = lrelu(asrc[c * HEADS + h0] + ad0, 0.2f);
    float e1 = lrelu(asrc[c * HEADS + h1] + ad1, 0.2f);
    float w0 = expf(e0 - m0) * r0;
    float w1 = expf(e1 - m1) * r1;
    acc0 = fmaf(w0, xr[d0], acc0);
    acc1 = fmaf(w1, xr[d1], acc1);
  }
  hout[(size_t)n * DIM + d0] = lrelu(acc0 + bias[d0], 0.01f);
  hout[(size_t)n * DIM + d1] = lrelu(acc1 + bias[d1], 0.01f);
}

// ---------------- score MLP: one wave per node ----------------
__global__ __launch_bounds__(256) void k_score(const float* __restrict__ h2,
                                               const float* __restrict__ wm1, const float* __restrict__ bm1,
                                               const float* __restrict__ wm2, const float* __restrict__ bm2,
                                               float* __restrict__ scores, int N) {
  __shared__ float sw[DIM * 64];
  int tid = threadIdx.x;
  for (int i = tid; i < DIM * 64; i += 256) sw[i] = wm1[i];
  __syncthreads();
  int lane = tid & 63, wv = tid >> 6;
  float b1v = bm1[lane], w2v = wm2[lane], b2v = bm2[0];
  for (int n = blockIdx.x * 4 + wv; n < N; n += gridDim.x * 4) {
    const float* hr = h2 + (size_t)n * DIM;
    float acc = 0.f;
#pragma unroll 4
    for (int k = 0; k < DIM; ++k) acc = fmaf(hr[k], sw[k * 64 + lane], acc);
    float p = lrelu(acc + b1v, 0.01f) * w2v;
#pragma unroll
    for (int off = 32; off; off >>= 1) p += __shfl_xor(p, off, 64);
    if (lane == 0) scores[n] = p + b2v;
  }
}

// ---------------- global softmax + weighted aggregation ----------------
__global__ __launch_bounds__(256) void k_pmax(const float* __restrict__ sc, int N, float* __restrict__ pmax) {
  __shared__ float red[256];
  int tid = threadIdx.x;
  float m = -INFINITY;
  for (int i = blockIdx.x * 256 + tid; i < N; i += 256 * gridDim.x) m = fmaxf(m, sc[i]);
  red[tid] = m; __syncthreads();
  for (int st = 128; st > 0; st >>= 1) { if (tid < st) red[tid] = fmaxf(red[tid], red[tid + st]); __syncthreads(); }
  if (tid == 0) pmax[blockIdx.x] = red[0];
}

__global__ __launch_bounds__(256) void k_gmax(const float* __restrict__ p, int n, float* __restrict__ g) {
  __shared__ float red[256];
  int tid = threadIdx.x;
  red[tid] = (tid < n) ? p[tid] : -INFINITY; __syncthreads();
  for (int st = 128; st > 0; st >>= 1) { if (tid < st) red[tid] = fmaxf(red[tid], red[tid + st]); __syncthreads(); }
  if (tid == 0) g[0] = red[0];
}

__global__ __launch_bounds__(256) void k_expsum(const float* __restrict__ sc, int N, const float* __restrict__ gM,
                                                float* __restrict__ wun, float* __restrict__ psum) {
  __shared__ float red[256];
  int tid = threadIdx.x;
  float M = gM[0];
  float s = 0.f;
  for (int i = blockIdx.x * 256 + tid; i < N; i += 256 * gridDim.x) {
    float e = expf(sc[i] - M);
    wun[i] = e;
    s += e;
  }
  red[tid] = s; __syncthreads();
  for (int st = 128; st > 0; st >>= 1) { if (tid < st) red[tid] += red[tid + st]; __syncthreads(); }
  if (tid == 0) psum[blockIdx.x] = red[0];
}

__global__ __launch_bounds__(256) void k_gsum(const float* __restrict__ p, int n, float* __restrict__ g) {
  __shared__ float red[256];
  int tid = threadIdx.x;
  red[tid] = (tid < n) ? p[tid] : 0.f; __syncthreads();
  for (int st = 128; st > 0; st >>= 1) { if (tid < st) red[tid] += red[tid + st]; __syncthreads(); }
  if (tid == 0) g[0] = red[0];
}

__global__ __launch_bounds__(128) void k_wagg(const float* __restrict__ wun, const float* __restrict__ h2,
                                              int N, float* __restrict__ agg) {
  int d = threadIdx.x;
  float acc = 0.f;
  for (int n = blockIdx.x; n < N; n += gridDim.x) acc += wun[n] * h2[(size_t)n * DIM + d];
  atomicAdd(&agg[d], acc);
}

// ---------------- final MLP + layernorm (single block, 128 threads) ----------------
__global__ __launch_bounds__(128) void k_final(const float* __restrict__ agg, const float* __restrict__ gZ,
                                               const float* __restrict__ wa1, const float* __restrict__ ba1,
                                               const float* __restrict__ wa2, const float* __restrict__ ba2,
                                               const float* __restrict__ gamma, const float* __restrict__ beta,
                                               float* __restrict__ out) {
  __shared__ float sa[128], sh[64], red[128];
  int t = threadIdx.x;
  float Z = gZ[0];
  sa[t] = agg[t] / Z;
  __syncthreads();
  if (t < 64) {
    float a = 0.f;
    for (int k = 0; k < 128; ++k) a = fmaf(sa[k], wa1[k * 64 + t], a);
    a += ba1[t];
    sh[t] = lrelu(a, 0.01f);
  }
  __syncthreads();
  float z = ba2[t];
  for (int j = 0; j < 64; ++j) z = fmaf(sh[j], wa2[j * 128 + t], z);
  red[t] = z; __syncthreads();
  for (int st = 64; st > 0; st >>= 1) { if (t < st) red[t] += red[t + st]; __syncthreads(); }
  float mu = red[0] / 128.f;
  __syncthreads();
  red[t] = (z - mu) * (z - mu); __syncthreads();
  for (int st = 64; st > 0; st >>= 1) { if (t < st) red[t] += red[t + st]; __syncthreads(); }
  float var = red[0] / 128.f;
  out[t] = gamma[t] * (z - mu) / sqrtf(var + 1e-5f) + beta[t];
}

extern "C" void kernel_launch(void* const* d_in, const int* in_sizes, int n_in,
                              void* d_out, int out_size, void* d_ws, size_t ws_size,
                              hipStream_t stream) {
  const float* feat = (const float*)d_in[0];
  const int* ei = (const int*)d_in[1];
  const float* W1 = (const float*)d_in[2];
  const float* as1 = (const float*)d_in[3];
  const float* ad1 = (const float*)d_in[4];
  const float* b1 = (const float*)d_in[5];
  const float* W2 = (const float*)d_in[6];
  const float* as2 = (const float*)d_in[7];
  const float* ad2 = (const float*)d_in[8];
  const float* b2 = (const float*)d_in[9];
  const float* wm1 = (const float*)d_in[10];
  const float* bm1 = (const float*)d_in[11];
  const float* wm2 = (const float*)d_in[12];
  const float* bm2 = (const float*)d_in[13];
  const float* wa1 = (const float*)d_in[14];
  const float* ba1 = (const float*)d_in[15];
  const float* wa2 = (const float*)d_in[16];
  const float* ba2 = (const float*)d_in[17];
  const float* gamma = (const float*)d_in[18];
  const float* beta = (const float*)d_in[19];
  float* out = (float*)d_out;

  int N = in_sizes[0] / DIM;   // 50000
  int E = in_sizes[1] / 2;     // 600000
  int NB = (N + 255) / 256;    // scan blocks

  char* ws = (char*)d_ws;
  size_t off = 0;
  auto alloc = [&](size_t bytes) -> void* {
    void* p = ws + off;
    off = (off + bytes + 255) & ~(size_t)255;
    return p;
  };
  int* cnt = (int*)alloc((size_t)N * 4);
  int* rowptr = (int*)alloc((size_t)(N + 1) * 4);
  int* cursor = (int*)alloc((size_t)N * 4);  // also serves as excl-scan temp
  int* colb = (int*)alloc((size_t)(E + N) * 4);
  float* xh = (float*)alloc((size_t)N * DIM * 4);
  float* h1 = (float*)alloc((size_t)N * DIM * 4);
  float* h2 = (float*)alloc((size_t)N * DIM * 4);
  float* asrcb = (float*)alloc((size_t)N * HEADS * 4);
  float* adstb = (float*)alloc((size_t)N * HEADS * 4);
  float* scores = (float*)alloc((size_t)N * 4);
  float* wun = (float*)alloc((size_t)N * 4);
  float* pmax = (float*)alloc(256 * 4);
  float* psum = (float*)alloc(256 * 4);
  float* gM = (float*)alloc(4);
  float* gZ = (float*)alloc(4);
  float* agg = (float*)alloc(DIM * 4);
  int* bsum = (int*)alloc((size_t)NB * 4);
  int* boff = (int*)alloc((size_t)NB * 4);
  unsigned short* wh1 = (unsigned short*)alloc(DIM * DIM * 2);
  unsigned short* wl1 = (unsigned short*)alloc(DIM * DIM * 2);
  unsigned short* sh1 = (unsigned short*)alloc(16 * DIM * 2);
  unsigned short* sl1 = (unsigned short*)alloc(16 * DIM * 2);
  unsigned short* wh2 = (unsigned short*)alloc(DIM * DIM * 2);
  unsigned short* wl2 = (unsigned short*)alloc(DIM * DIM * 2);
  unsigned short* sh2 = (unsigned short*)alloc(16 * DIM * 2);
  unsigned short* sl2 = (unsigned short*)alloc(16 * DIM * 2);

  hipMemsetAsync(cnt, 0, (size_t)N * 4, stream);
  hipMemsetAsync(agg, 0, DIM * 4, stream);

  k_wprep<<<1, 256, 0, stream>>>(W1, as1, ad1, wh1, wl1, sh1, sl1);
  k_wprep<<<1, 256, 0, stream>>>(W2, as2, ad2, wh2, wl2, sh2, sl2);

  k_hist<<<1024, 256, 0, stream>>>(ei, E, N, cnt);
  k_scan_blk<<<NB, 256, 0, stream>>>(cnt, N, cursor, bsum);
  k_scan_top<<<1, 256, 0, stream>>>(bsum, NB, boff, rowptr + N);
  k_scan_fix<<<NB, 256, 0, stream>>>(cursor, boff, N, rowptr);
  k_scatter<<<1024, 256, 0, stream>>>(ei, E, N, cursor, colb);

  int gl = (N + 63) / 64;
  int ga = (N + 3) / 4;
  k_linear_mfma<<<gl, 256, 0, stream>>>(feat, wh1, wl1, sh1, sl1, xh, asrcb, adstb, N);
  k_gat_agg<<<ga, 256, 0, stream>>>(rowptr, colb, xh, asrcb, adstb, b1, h1, N);
  k_linear_mfma<<<gl, 256, 0, stream>>>(h1, wh2, wl2, sh2, sl2, xh, asrcb, adstb, N);
  k_gat_agg<<<ga, 256, 0, stream>>>(rowptr, colb, xh, asrcb, adstb, b2, h2, N);

  k_score<<<2048, 256, 0, stream>>>(h2, wm1, bm1, wm2, bm2, scores, N);
  k_pmax<<<256, 256, 0, stream>>>(scores, N, pmax);
  k_gmax<<<1, 256, 0, stream>>>(pmax, 256, gM);
  k_expsum<<<256, 256, 0, stream>>>(scores, N, gM, wun, psum);
  k_gsum<<<1, 256, 0, stream>>>(psum, 256, gZ);
  k_wagg<<<256, 128, 0, stream>>>(wun, h2, N, agg);
  k_final<<<1, 128, 0, stream>>>(agg, gZ, wa1, ba1, wa2, ba2, gamma, beta, out);
}

// Round 3
// 458.374 us; speedup vs baseline: 1.5647x; 1.1824x over previous
//
#include <hip/hip_runtime.h>
#include <math.h>

#define DIM 128
#define HEADS 8
#define HD 16
#define CAP 64

typedef __attribute__((ext_vector_type(8))) short s16x8;
typedef __attribute__((ext_vector_type(4))) float f32x4;

__device__ __forceinline__ float lrelu(float x, float s) { return x >= 0.f ? x : s * x; }

__device__ __forceinline__ unsigned short f2bf(float x) {
  unsigned u = __float_as_uint(x);
  return (unsigned short)((u + 0x7FFFu + ((u >> 16) & 1u)) >> 16);
}
__device__ __forceinline__ float bf2f(unsigned short b) {
  return __uint_as_float(((unsigned)b) << 16);
}

// ---------------- CSR build (group edges by destination) ----------------
__global__ void k_hist(const int* __restrict__ ei, int E, int N, int* __restrict__ cnt) {
  int tot = E + N;
  for (int i = blockIdx.x * blockDim.x + threadIdx.x; i < tot; i += gridDim.x * blockDim.x) {
    int d = (i < E) ? ei[E + i] : (i - E);  // self-loops appended
    atomicAdd(&cnt[d], 1);
  }
}

__global__ __launch_bounds__(256) void k_scan_blk(const int* __restrict__ cnt, int n,
                                                  int* __restrict__ excl, int* __restrict__ bsum) {
  __shared__ int wsum[4];
  int tid = threadIdx.x, l = tid & 63, w = tid >> 6;
  int i = blockIdx.x * 256 + tid;
  int v = (i < n) ? cnt[i] : 0;
  int s = v;
#pragma unroll
  for (int off = 1; off < 64; off <<= 1) {
    int t = __shfl_up(s, off, 64);
    if (l >= off) s += t;
  }
  if (l == 63) wsum[w] = s;
  __syncthreads();
  int add = 0;
#pragma unroll
  for (int k = 0; k < 4; ++k) add += (k < w) ? wsum[k] : 0;
  if (i < n) excl[i] = s + add - v;
  if (tid == 255) bsum[blockIdx.x] = s + add;
}

__global__ __launch_bounds__(256) void k_scan_top(const int* __restrict__ bsum, int nb,
                                                  int* __restrict__ boff, int* __restrict__ rowptrN) {
  __shared__ int wsum[4];
  int tid = threadIdx.x, l = tid & 63, w = tid >> 6;
  int v = (tid < nb) ? bsum[tid] : 0;
  int s = v;
#pragma unroll
  for (int off = 1; off < 64; off <<= 1) {
    int t = __shfl_up(s, off, 64);
    if (l >= off) s += t;
  }
  if (l == 63) wsum[w] = s;
  __syncthreads();
  int add = 0;
#pragma unroll
  for (int k = 0; k < 4; ++k) add += (k < w) ? wsum[k] : 0;
  if (tid < nb) boff[tid] = s + add - v;
  if (tid == 255) *rowptrN = s + add;
}

__global__ __launch_bounds__(256) void k_scan_fix(int* __restrict__ cursor, const int* __restrict__ boff,
                                                  int n, int* __restrict__ rowptr) {
  int i = blockIdx.x * 256 + threadIdx.x;
  if (i < n) {
    int r = boff[blockIdx.x] + cursor[i];
    rowptr[i] = r;
    cursor[i] = r;
  }
}

__global__ void k_scatter(const int* __restrict__ ei, int E, int N,
                          int* __restrict__ cursor, int* __restrict__ colb) {
  int tot = E + N;
  for (int i = blockIdx.x * blockDim.x + threadIdx.x; i < tot; i += gridDim.x * blockDim.x) {
    int s, d;
    if (i < E) { s = ei[i]; d = ei[E + i]; } else { s = i - E; d = s; }
    int pos = atomicAdd(&cursor[d], 1);
    colb[pos] = s;
  }
}

// ---------------- weight prep: W^T fragments (split bf16 hi/lo) + alpha-proj cols ----------------
__global__ __launch_bounds__(256) void k_wprep(const float* __restrict__ W,
                                               const float* __restrict__ av_s, const float* __restrict__ av_d,
                                               unsigned short* __restrict__ wh, unsigned short* __restrict__ wl,
                                               unsigned short* __restrict__ sh, unsigned short* __restrict__ sl) {
  int tid = threadIdx.x;
  for (int idx = tid; idx < DIM * DIM; idx += 256) {
    int n = idx >> 7, k = idx & 127;
    float v = W[k * DIM + n];
    unsigned short hb = f2bf(v);
    wh[idx] = hb;
    wl[idx] = f2bf(v - bf2f(hb));
  }
  for (int idx = tid; idx < 16 * DIM; idx += 256) {
    int n = idx >> 7, k = idx & 127;
    float acc = 0.f;
    if (n < 8) {
#pragma unroll
      for (int j = 0; j < 16; ++j) acc += W[k * DIM + n * 16 + j] * av_s[n * 16 + j];
    } else {
      int h = n - 8;
#pragma unroll
      for (int j = 0; j < 16; ++j) acc += W[k * DIM + h * 16 + j] * av_d[h * 16 + j];
    }
    unsigned short hb = f2bf(acc);
    sh[idx] = hb;
    sl[idx] = f2bf(acc - bf2f(hb));
  }
}

// ---------------- xh = x @ W via split-bf16 MFMA; xh stored as bf16; alphas fused ----------------
__global__ __launch_bounds__(256) void k_linear_mfma(
    const float* __restrict__ x,
    const unsigned short* __restrict__ wh, const unsigned short* __restrict__ wl,
    const unsigned short* __restrict__ sh, const unsigned short* __restrict__ sl,
    unsigned short* __restrict__ xhb, float* __restrict__ asrc, float* __restrict__ adst, int N) {
  int tid = threadIdx.x, l = tid & 63, w = tid >> 6;
  int g = l >> 4, c = l & 15;
  int rbase = blockIdx.x * 64 + w * 16;
  int row = rbase + c;
  int rc = min(row, N - 1);
  const float4* xf = (const float4*)(x + (size_t)rc * DIM);

  s16x8 Ah[4], Al[4];
#pragma unroll
  for (int kt = 0; kt < 4; ++kt) {
    float4 p = xf[kt * 8 + g * 2];
    float4 q = xf[kt * 8 + g * 2 + 1];
    s16x8 ah, al;
#define CV(v, j) { unsigned short hb = f2bf(v); ah[j] = (short)hb; al[j] = (short)f2bf((v) - bf2f(hb)); }
    CV(p.x, 0) CV(p.y, 1) CV(p.z, 2) CV(p.w, 3)
    CV(q.x, 4) CV(q.y, 5) CV(q.z, 6) CV(q.w, 7)
#undef CV
    Ah[kt] = ah;
    Al[kt] = al;
  }

  const s16x8* Bh = (const s16x8*)wh;
  const s16x8* Bl = (const s16x8*)wl;
#pragma unroll
  for (int ct = 0; ct < 8; ++ct) {
    f32x4 acc = {0.f, 0.f, 0.f, 0.f};
    int nb = (ct * 16 + c) * 4;
#pragma unroll
    for (int kt = 0; kt < 4; ++kt) {
      s16x8 bh = Bh[(nb + kt) * 4 + g];
      s16x8 bl = Bl[(nb + kt) * 4 + g];
      acc = __builtin_amdgcn_mfma_f32_16x16x32_bf16(Ah[kt], bh, acc, 0, 0, 0);
      acc = __builtin_amdgcn_mfma_f32_16x16x32_bf16(Ah[kt], bl, acc, 0, 0, 0);
      acc = __builtin_amdgcn_mfma_f32_16x16x32_bf16(Al[kt], bh, acc, 0, 0, 0);
    }
#pragma unroll
    for (int r = 0; r < 4; ++r) {
      int rr = rbase + g * 4 + r;
      if (rr < N) xhb[(size_t)rr * DIM + ct * 16 + c] = f2bf(acc[r]);
    }
  }

  const s16x8* Shp = (const s16x8*)sh;
  const s16x8* Slp = (const s16x8*)sl;
  f32x4 acc = {0.f, 0.f, 0.f, 0.f};
#pragma unroll
  for (int kt = 0; kt < 4; ++kt) {
    s16x8 bh = Shp[(c * 4 + kt) * 4 + g];
    s16x8 bl = Slp[(c * 4 + kt) * 4 + g];
    acc = __builtin_amdgcn_mfma_f32_16x16x32_bf16(Ah[kt], bh, acc, 0, 0, 0);
    acc = __builtin_amdgcn_mfma_f32_16x16x32_bf16(Ah[kt], bl, acc, 0, 0, 0);
    acc = __builtin_amdgcn_mfma_f32_16x16x32_bf16(Al[kt], bh, acc, 0, 0, 0);
  }
#pragma unroll
  for (int r = 0; r < 4; ++r) {
    int rr = rbase + g * 4 + r;
    if (rr < N) {
      if (c < 8) asrc[rr * HEADS + c] = acc[r];
      else adst[rr * HEADS + (c - 8)] = acc[r];
    }
  }
}

// ---------------- GAT aggregation: one wave per destination node ----------------
// Single exp pass (no segment-max needed: |e| <= ~4, exp can't overflow; softmax
// ratio is max-shift invariant). exp(e) cached in LDS; denominator via shfl.
__global__ __launch_bounds__(256) void k_gat_agg(const int* __restrict__ rowptr, const int* __restrict__ colb,
                                                 const unsigned short* __restrict__ xhb,
                                                 const float* __restrict__ asrc, const float* __restrict__ adst,
                                                 const float* __restrict__ bias,
                                                 float* __restrict__ hout, int N) {
  __shared__ float ew[4][CAP][8];
  __shared__ float sdenom[4][8];
  int tid = threadIdx.x, lane = tid & 63, wv = tid >> 6;
  int n = blockIdx.x * 4 + wv;
  int base = 0, deg = 0;
  if (n < N) { base = rowptr[n]; deg = rowptr[n + 1] - base; }
  int g = lane >> 3, ha = lane & 7;
  float adst_a = (n < N) ? adst[n * HEADS + ha] : 0.f;
  float s = 0.f;
  for (int i = g; i < deg; i += 8) {
    int c = colb[base + i];
    float e = lrelu(asrc[c * HEADS + ha] + adst_a, 0.2f);
    float x = __expf(e);
    if (i < CAP) ew[wv][i][ha] = x;
    s += x;
  }
  s += __shfl_xor(s, 8, 64);
  s += __shfl_xor(s, 16, 64);
  s += __shfl_xor(s, 32, 64);
  if (g == 0) sdenom[wv][ha] = s + 1e-16f;
  __syncthreads();
  if (n >= N) return;
  int h = lane >> 3;                 // head for dims 2*lane, 2*lane+1
  float r = 1.f / sdenom[wv][h];
  float adh = adst_a;                // only used on fallback path (h==ha never guaranteed; reload)
  float acc0 = 0.f, acc1 = 0.f;
  const unsigned short* xrow;
  for (int i = 0; i < deg; ++i) {
    int c = colb[base + i];
    float wgt;
    if (i < CAP) {
      wgt = ew[wv][i][h] * r;
    } else {  // practically never hit (deg ~ Poisson(12)+1)
      float e = lrelu(asrc[c * HEADS + h] + adst[n * HEADS + h], 0.2f);
      wgt = __expf(e) * r;
    }
    unsigned u = *(const unsigned*)(xhb + (size_t)c * DIM + lane * 2);
    float f0 = __uint_as_float(u << 16);
    float f1 = __uint_as_float(u & 0xffff0000u);
    acc0 = fmaf(wgt, f0, acc0);
    acc1 = fmaf(wgt, f1, acc1);
  }
  (void)adh; (void)xrow;
  float2 o;
  o.x = lrelu(acc0 + bias[lane * 2], 0.01f);
  o.y = lrelu(acc1 + bias[lane * 2 + 1], 0.01f);
  *(float2*)(hout + (size_t)n * DIM + lane * 2) = o;
}

// ---------------- score MLP: one wave per node ----------------
__global__ __launch_bounds__(256) void k_score(const float* __restrict__ h2,
                                               const float* __restrict__ wm1, const float* __restrict__ bm1,
                                               const float* __restrict__ wm2, const float* __restrict__ bm2,
                                               float* __restrict__ scores, int N) {
  __shared__ float sw[DIM * 64];
  int tid = threadIdx.x;
  for (int i = tid; i < DIM * 64; i += 256) sw[i] = wm1[i];
  __syncthreads();
  int lane = tid & 63, wv = tid >> 6;
  float b1v = bm1[lane], w2v = wm2[lane], b2v = bm2[0];
  for (int n = blockIdx.x * 4 + wv; n < N; n += gridDim.x * 4) {
    const float* hr = h2 + (size_t)n * DIM;
    float acc = 0.f;
#pragma unroll 4
    for (int k = 0; k < DIM; ++k) acc = fmaf(hr[k], sw[k * 64 + lane], acc);
    float p = lrelu(acc + b1v, 0.01f) * w2v;
#pragma unroll
    for (int off = 32; off; off >>= 1) p += __shfl_xor(p, off, 64);
    if (lane == 0) scores[n] = p + b2v;
  }
}

// ---------------- global softmax + weighted aggregation ----------------
__global__ __launch_bounds__(256) void k_pmax(const float* __restrict__ sc, int N, float* __restrict__ pmax) {
  __shared__ float red[256];
  int tid = threadIdx.x;
  float m = -INFINITY;
  for (int i = blockIdx.x * 256 + tid; i < N; i += 256 * gridDim.x) m = fmaxf(m, sc[i]);
  red[tid] = m; __syncthreads();
  for (int st = 128; st > 0; st >>= 1) { if (tid < st) red[tid] = fmaxf(red[tid], red[tid + st]); __syncthreads(); }
  if (tid == 0) pmax[blockIdx.x] = red[0];
}

__global__ __launch_bounds__(256) void k_gmax(const float* __restrict__ p, int n, float* __restrict__ g) {
  __shared__ float red[256];
  int tid = threadIdx.x;
  red[tid] = (tid < n) ? p[tid] : -INFINITY; __syncthreads();
  for (int st = 128; st > 0; st >>= 1) { if (tid < st) red[tid] = fmaxf(red[tid], red[tid + st]); __syncthreads(); }
  if (tid == 0) g[0] = red[0];
}

__global__ __launch_bounds__(256) void k_expsum(const float* __restrict__ sc, int N, const float* __restrict__ gM,
                                                float* __restrict__ wun, float* __restrict__ psum) {
  __shared__ float red[256];
  int tid = threadIdx.x;
  float M = gM[0];
  float s = 0.f;
  for (int i = blockIdx.x * 256 + tid; i < N; i += 256 * gridDim.x) {
    float e = __expf(sc[i] - M);
    wun[i] = e;
    s += e;
  }
  red[tid] = s; __syncthreads();
  for (int st = 128; st > 0; st >>= 1) { if (tid < st) red[tid] += red[tid + st]; __syncthreads(); }
  if (tid == 0) psum[blockIdx.x] = red[0];
}

__global__ __launch_bounds__(256) void k_gsum(const float* __restrict__ p, int n, float* __restrict__ g) {
  __shared__ float red[256];
  int tid = threadIdx.x;
  red[tid] = (tid < n) ? p[tid] : 0.f; __syncthreads();
  for (int st = 128; st > 0; st >>= 1) { if (tid < st) red[tid] += red[tid + st]; __syncthreads(); }
  if (tid == 0) g[0] = red[0];
}

__global__ __launch_bounds__(128) void k_wagg(const float* __restrict__ wun, const float* __restrict__ h2,
                                              int N, float* __restrict__ agg) {
  int d = threadIdx.x;
  float acc = 0.f;
  for (int n = blockIdx.x; n < N; n += gridDim.x) acc += wun[n] * h2[(size_t)n * DIM + d];
  atomicAdd(&agg[d], acc);
}

// ---------------- final MLP + layernorm (single block, 128 threads) ----------------
__global__ __launch_bounds__(128) void k_final(const float* __restrict__ agg, const float* __restrict__ gZ,
                                               const float* __restrict__ wa1, const float* __restrict__ ba1,
                                               const float* __restrict__ wa2, const float* __restrict__ ba2,
                                               const float* __restrict__ gamma, const float* __restrict__ beta,
                                               float* __restrict__ out) {
  __shared__ float sa[128], sh[64], red[128];
  int t = threadIdx.x;
  float Z = gZ[0];
  sa[t] = agg[t] / Z;
  __syncthreads();
  if (t < 64) {
    float a = 0.f;
    for (int k = 0; k < 128; ++k) a = fmaf(sa[k], wa1[k * 64 + t], a);
    a += ba1[t];
    sh[t] = lrelu(a, 0.01f);
  }
  __syncthreads();
  float z = ba2[t];
  for (int j = 0; j < 64; ++j) z = fmaf(sh[j], wa2[j * 128 + t], z);
  red[t] = z; __syncthreads();
  for (int st = 64; st > 0; st >>= 1) { if (t < st) red[t] += red[t + st]; __syncthreads(); }
  float mu = red[0] / 128.f;
  __syncthreads();
  red[t] = (z - mu) * (z - mu); __syncthreads();
  for (int st = 64; st > 0; st >>= 1) { if (t < st) red[t] += red[t + st]; __syncthreads(); }
  float var = red[0] / 128.f;
  out[t] = gamma[t] * (z - mu) / sqrtf(var + 1e-5f) + beta[t];
}

extern "C" void kernel_launch(void* const* d_in, const int* in_sizes, int n_in,
                              void* d_out, int out_size, void* d_ws, size_t ws_size,
                              hipStream_t stream) {
  const float* feat = (const float*)d_in[0];
  const int* ei = (const int*)d_in[1];
  const float* W1 = (const float*)d_in[2];
  const float* as1 = (const float*)d_in[3];
  const float* ad1 = (const float*)d_in[4];
  const float* b1 = (const float*)d_in[5];
  const float* W2 = (const float*)d_in[6];
  const float* as2 = (const float*)d_in[7];
  const float* ad2 = (const float*)d_in[8];
  const float* b2 = (const float*)d_in[9];
  const float* wm1 = (const float*)d_in[10];
  const float* bm1 = (const float*)d_in[11];
  const float* wm2 = (const float*)d_in[12];
  const float* bm2 = (const float*)d_in[13];
  const float* wa1 = (const float*)d_in[14];
  const float* ba1 = (const float*)d_in[15];
  const float* wa2 = (const float*)d_in[16];
  const float* ba2 = (const float*)d_in[17];
  const float* gamma = (const float*)d_in[18];
  const float* beta = (const float*)d_in[19];
  float* out = (float*)d_out;

  int N = in_sizes[0] / DIM;   // 50000
  int E = in_sizes[1] / 2;     // 600000
  int NB = (N + 255) / 256;

  char* ws = (char*)d_ws;
  size_t off = 0;
  auto alloc = [&](size_t bytes) -> void* {
    void* p = ws + off;
    off = (off + bytes + 255) & ~(size_t)255;
    return p;
  };
  int* cnt = (int*)alloc((size_t)N * 4);
  int* rowptr = (int*)alloc((size_t)(N + 1) * 4);
  int* cursor = (int*)alloc((size_t)N * 4);
  int* colb = (int*)alloc((size_t)(E + N) * 4);
  unsigned short* xhb = (unsigned short*)alloc((size_t)N * DIM * 2);
  float* h1 = (float*)alloc((size_t)N * DIM * 4);
  float* h2 = (float*)alloc((size_t)N * DIM * 4);
  float* asrcb = (float*)alloc((size_t)N * HEADS * 4);
  float* adstb = (float*)alloc((size_t)N * HEADS * 4);
  float* scores = (float*)alloc((size_t)N * 4);
  float* wun = (float*)alloc((size_t)N * 4);
  float* pmax = (float*)alloc(256 * 4);
  float* psum = (float*)alloc(256 * 4);
  float* gM = (float*)alloc(4);
  float* gZ = (float*)alloc(4);
  float* agg = (float*)alloc(DIM * 4);
  int* bsum = (int*)alloc((size_t)NB * 4);
  int* boff = (int*)alloc((size_t)NB * 4);
  unsigned short* wh1 = (unsigned short*)alloc(DIM * DIM * 2);
  unsigned short* wl1 = (unsigned short*)alloc(DIM * DIM * 2);
  unsigned short* sh1 = (unsigned short*)alloc(16 * DIM * 2);
  unsigned short* sl1 = (unsigned short*)alloc(16 * DIM * 2);
  unsigned short* wh2 = (unsigned short*)alloc(DIM * DIM * 2);
  unsigned short* wl2 = (unsigned short*)alloc(DIM * DIM * 2);
  unsigned short* sh2 = (unsigned short*)alloc(16 * DIM * 2);
  unsigned short* sl2 = (unsigned short*)alloc(16 * DIM * 2);

  hipMemsetAsync(cnt, 0, (size_t)N * 4, stream);
  hipMemsetAsync(agg, 0, DIM * 4, stream);

  k_wprep<<<1, 256, 0, stream>>>(W1, as1, ad1, wh1, wl1, sh1, sl1);
  k_wprep<<<1, 256, 0, stream>>>(W2, as2, ad2, wh2, wl2, sh2, sl2);

  k_hist<<<1024, 256, 0, stream>>>(ei, E, N, cnt);
  k_scan_blk<<<NB, 256, 0, stream>>>(cnt, N, cursor, bsum);
  k_scan_top<<<1, 256, 0, stream>>>(bsum, NB, boff, rowptr + N);
  k_scan_fix<<<NB, 256, 0, stream>>>(cursor, boff, N, rowptr);
  k_scatter<<<1024, 256, 0, stream>>>(ei, E, N, cursor, colb);

  int gl = (N + 63) / 64;
  int ga = (N + 3) / 4;
  k_linear_mfma<<<gl, 256, 0, stream>>>(feat, wh1, wl1, sh1, sl1, xhb, asrcb, adstb, N);
  k_gat_agg<<<ga, 256, 0, stream>>>(rowptr, colb, xhb, asrcb, adstb, b1, h1, N);
  k_linear_mfma<<<gl, 256, 0, stream>>>(h1, wh2, wl2, sh2, sl2, xhb, asrcb, adstb, N);
  k_gat_agg<<<ga, 256, 0, stream>>>(rowptr, colb, xhb, asrcb, adstb, b2, h2, N);

  k_score<<<2048, 256, 0, stream>>>(h2, wm1, bm1, wm2, bm2, scores, N);
  k_pmax<<<256, 256, 0, stream>>>(scores, N, pmax);
  k_gmax<<<1, 256, 0, stream>>>(pmax, 256, gM);
  k_expsum<<<256, 256, 0, stream>>>(scores, N, gM, wun, psum);
  k_gsum<<<1, 256, 0, stream>>>(psum, 256, gZ);
  k_wagg<<<256, 128, 0, stream>>>(wun, h2, N, agg);
  k_final<<<1, 128, 0, stream>>>(agg, gZ, wa1, ba1, wa2, ba2, gamma, beta, out);
}

// Round 4
// 392.063 us; speedup vs baseline: 1.8294x; 1.1691x over previous
//
#include <hip/hip_runtime.h>
#include <math.h>

#define DIM 128
#define HEADS 8
#define HD 16
#define CAP 64

typedef __attribute__((ext_vector_type(8))) short s16x8;
typedef __attribute__((ext_vector_type(4))) float f32x4;

__device__ __forceinline__ float lrelu(float x, float s) { return x >= 0.f ? x : s * x; }

__device__ __forceinline__ unsigned short f2bf(float x) {
  unsigned u = __float_as_uint(x);
  return (unsigned short)((u + 0x7FFFu + ((u >> 16) & 1u)) >> 16);
}
__device__ __forceinline__ float bf2f(unsigned short b) {
  return __uint_as_float(((unsigned)b) << 16);
}

// ---------------- CSR build (group edges by destination) ----------------
__global__ void k_hist(const int* __restrict__ ei, int E, int N, int* __restrict__ cnt) {
  int tot = E + N;
  for (int i = blockIdx.x * blockDim.x + threadIdx.x; i < tot; i += gridDim.x * blockDim.x) {
    int d = (i < E) ? ei[E + i] : (i - E);  // self-loops appended
    atomicAdd(&cnt[d], 1);
  }
}

__global__ __launch_bounds__(256) void k_scan_blk(const int* __restrict__ cnt, int n,
                                                  int* __restrict__ excl, int* __restrict__ bsum) {
  __shared__ int wsum[4];
  int tid = threadIdx.x, l = tid & 63, w = tid >> 6;
  int i = blockIdx.x * 256 + tid;
  int v = (i < n) ? cnt[i] : 0;
  int s = v;
#pragma unroll
  for (int off = 1; off < 64; off <<= 1) {
    int t = __shfl_up(s, off, 64);
    if (l >= off) s += t;
  }
  if (l == 63) wsum[w] = s;
  __syncthreads();
  int add = 0;
#pragma unroll
  for (int k = 0; k < 4; ++k) add += (k < w) ? wsum[k] : 0;
  if (i < n) excl[i] = s + add - v;
  if (tid == 255) bsum[blockIdx.x] = s + add;
}

__global__ __launch_bounds__(256) void k_scan_top(const int* __restrict__ bsum, int nb,
                                                  int* __restrict__ boff, int* __restrict__ rowptrN) {
  __shared__ int wsum[4];
  int tid = threadIdx.x, l = tid & 63, w = tid >> 6;
  int v = (tid < nb) ? bsum[tid] : 0;
  int s = v;
#pragma unroll
  for (int off = 1; off < 64; off <<= 1) {
    int t = __shfl_up(s, off, 64);
    if (l >= off) s += t;
  }
  if (l == 63) wsum[w] = s;
  __syncthreads();
  int add = 0;
#pragma unroll
  for (int k = 0; k < 4; ++k) add += (k < w) ? wsum[k] : 0;
  if (tid < nb) boff[tid] = s + add - v;
  if (tid == 255) *rowptrN = s + add;
}

__global__ __launch_bounds__(256) void k_scan_fix(int* __restrict__ cursor, const int* __restrict__ boff,
                                                  int n, int* __restrict__ rowptr) {
  int i = blockIdx.x * 256 + threadIdx.x;
  if (i < n) {
    int r = boff[blockIdx.x] + cursor[i];
    rowptr[i] = r;
    cursor[i] = r;
  }
}

__global__ void k_scatter(const int* __restrict__ ei, int E, int N,
                          int* __restrict__ cursor, int* __restrict__ colb) {
  int tot = E + N;
  for (int i = blockIdx.x * blockDim.x + threadIdx.x; i < tot; i += gridDim.x * blockDim.x) {
    int s, d;
    if (i < E) { s = ei[i]; d = ei[E + i]; } else { s = i - E; d = s; }
    int pos = atomicAdd(&cursor[d], 1);
    colb[pos] = s;
  }
}

// ---------------- weight prep: W^T fragments (split bf16 hi/lo) + alpha-proj cols ----------------
__global__ __launch_bounds__(256) void k_wprep(const float* __restrict__ W,
                                               const float* __restrict__ av_s, const float* __restrict__ av_d,
                                               unsigned short* __restrict__ wh, unsigned short* __restrict__ wl,
                                               unsigned short* __restrict__ sh, unsigned short* __restrict__ sl) {
  int tid = threadIdx.x;
  for (int idx = tid; idx < DIM * DIM; idx += 256) {
    int n = idx >> 7, k = idx & 127;
    float v = W[k * DIM + n];
    unsigned short hb = f2bf(v);
    wh[idx] = hb;
    wl[idx] = f2bf(v - bf2f(hb));
  }
  for (int idx = tid; idx < 16 * DIM; idx += 256) {
    int n = idx >> 7, k = idx & 127;
    float acc = 0.f;
    if (n < 8) {
#pragma unroll
      for (int j = 0; j < 16; ++j) acc += W[k * DIM + n * 16 + j] * av_s[n * 16 + j];
    } else {
      int h = n - 8;
#pragma unroll
      for (int j = 0; j < 16; ++j) acc += W[k * DIM + h * 16 + j] * av_d[h * 16 + j];
    }
    unsigned short hb = f2bf(acc);
    sh[idx] = hb;
    sl[idx] = f2bf(acc - bf2f(hb));
  }
}

// ---------------- score-MLP weight prep: wm1^T split-bf16 fragments ----------------
__global__ __launch_bounds__(256) void k_mlpprep(const float* __restrict__ wm1,
                                                 unsigned short* __restrict__ mh, unsigned short* __restrict__ ml) {
  int tid = threadIdx.x;
  for (int idx = tid; idx < 64 * DIM; idx += 256) {
    int j = idx >> 7, k = idx & 127;   // mh[j][k] = wm1[k][j]
    float v = wm1[k * 64 + j];
    unsigned short hb = f2bf(v);
    mh[idx] = hb;
    ml[idx] = f2bf(v - bf2f(hb));
  }
}

// ---------------- xh = x @ W via split-bf16 MFMA; xh stored as bf16; alphas fused ----------------
__global__ __launch_bounds__(256) void k_linear_mfma(
    const float* __restrict__ x,
    const unsigned short* __restrict__ wh, const unsigned short* __restrict__ wl,
    const unsigned short* __restrict__ sh, const unsigned short* __restrict__ sl,
    unsigned short* __restrict__ xhb, float* __restrict__ asrc, float* __restrict__ adst, int N) {
  int tid = threadIdx.x, l = tid & 63, w = tid >> 6;
  int g = l >> 4, c = l & 15;
  int rbase = blockIdx.x * 64 + w * 16;
  int row = rbase + c;
  int rc = min(row, N - 1);
  const float4* xf = (const float4*)(x + (size_t)rc * DIM);

  s16x8 Ah[4], Al[4];
#pragma unroll
  for (int kt = 0; kt < 4; ++kt) {
    float4 p = xf[kt * 8 + g * 2];
    float4 q = xf[kt * 8 + g * 2 + 1];
    s16x8 ah, al;
#define CV(v, j) { unsigned short hb = f2bf(v); ah[j] = (short)hb; al[j] = (short)f2bf((v) - bf2f(hb)); }
    CV(p.x, 0) CV(p.y, 1) CV(p.z, 2) CV(p.w, 3)
    CV(q.x, 4) CV(q.y, 5) CV(q.z, 6) CV(q.w, 7)
#undef CV
    Ah[kt] = ah;
    Al[kt] = al;
  }

  const s16x8* Bh = (const s16x8*)wh;
  const s16x8* Bl = (const s16x8*)wl;
#pragma unroll
  for (int ct = 0; ct < 8; ++ct) {
    f32x4 acc = {0.f, 0.f, 0.f, 0.f};
    int nb = (ct * 16 + c) * 4;
#pragma unroll
    for (int kt = 0; kt < 4; ++kt) {
      s16x8 bh = Bh[(nb + kt) * 4 + g];
      s16x8 bl = Bl[(nb + kt) * 4 + g];
      acc = __builtin_amdgcn_mfma_f32_16x16x32_bf16(Ah[kt], bh, acc, 0, 0, 0);
      acc = __builtin_amdgcn_mfma_f32_16x16x32_bf16(Ah[kt], bl, acc, 0, 0, 0);
      acc = __builtin_amdgcn_mfma_f32_16x16x32_bf16(Al[kt], bh, acc, 0, 0, 0);
    }
#pragma unroll
    for (int r = 0; r < 4; ++r) {
      int rr = rbase + g * 4 + r;
      if (rr < N) xhb[(size_t)rr * DIM + ct * 16 + c] = f2bf(acc[r]);
    }
  }

  const s16x8* Shp = (const s16x8*)sh;
  const s16x8* Slp = (const s16x8*)sl;
  f32x4 acc = {0.f, 0.f, 0.f, 0.f};
#pragma unroll
  for (int kt = 0; kt < 4; ++kt) {
    s16x8 bh = Shp[(c * 4 + kt) * 4 + g];
    s16x8 bl = Slp[(c * 4 + kt) * 4 + g];
    acc = __builtin_amdgcn_mfma_f32_16x16x32_bf16(Ah[kt], bh, acc, 0, 0, 0);
    acc = __builtin_amdgcn_mfma_f32_16x16x32_bf16(Ah[kt], bl, acc, 0, 0, 0);
    acc = __builtin_amdgcn_mfma_f32_16x16x32_bf16(Al[kt], bh, acc, 0, 0, 0);
  }
#pragma unroll
  for (int r = 0; r < 4; ++r) {
    int rr = rbase + g * 4 + r;
    if (rr < N) {
      if (c < 8) asrc[rr * HEADS + c] = acc[r];
      else adst[rr * HEADS + (c - 8)] = acc[r];
    }
  }
}

// ---------------- GAT aggregation: one wave per destination node ----------------
__global__ __launch_bounds__(256) void k_gat_agg(const int* __restrict__ rowptr, const int* __restrict__ colb,
                                                 const unsigned short* __restrict__ xhb,
                                                 const float* __restrict__ asrc, const float* __restrict__ adst,
                                                 const float* __restrict__ bias,
                                                 float* __restrict__ hout, int N) {
  __shared__ float ew[4][CAP][8];
  __shared__ float sdenom[4][8];
  int tid = threadIdx.x, lane = tid & 63, wv = tid >> 6;
  int n = blockIdx.x * 4 + wv;
  int base = 0, deg = 0;
  if (n < N) { base = rowptr[n]; deg = rowptr[n + 1] - base; }
  int g = lane >> 3, ha = lane & 7;
  float adst_a = (n < N) ? adst[n * HEADS + ha] : 0.f;
  float s = 0.f;
  for (int i = g; i < deg; i += 8) {
    int c = colb[base + i];
    float e = lrelu(asrc[c * HEADS + ha] + adst_a, 0.2f);
    float x = __expf(e);
    if (i < CAP) ew[wv][i][ha] = x;
    s += x;
  }
  s += __shfl_xor(s, 8, 64);
  s += __shfl_xor(s, 16, 64);
  s += __shfl_xor(s, 32, 64);
  if (g == 0) sdenom[wv][ha] = s + 1e-16f;
  __syncthreads();
  if (n >= N) return;
  int h = lane >> 3;
  float r = 1.f / sdenom[wv][h];
  float acc0 = 0.f, acc1 = 0.f;
  for (int i = 0; i < deg; ++i) {
    int c = colb[base + i];
    float wgt;
    if (i < CAP) {
      wgt = ew[wv][i][h] * r;
    } else {
      float e = lrelu(asrc[c * HEADS + h] + adst[n * HEADS + h], 0.2f);
      wgt = __expf(e) * r;
    }
    unsigned u = *(const unsigned*)(xhb + (size_t)c * DIM + lane * 2);
    float f0 = __uint_as_float(u << 16);
    float f1 = __uint_as_float(u & 0xffff0000u);
    acc0 = fmaf(wgt, f0, acc0);
    acc1 = fmaf(wgt, f1, acc1);
  }
  float2 o;
  o.x = lrelu(acc0 + bias[lane * 2], 0.01f);
  o.y = lrelu(acc1 + bias[lane * 2 + 1], 0.01f);
  *(float2*)(hout + (size_t)n * DIM + lane * 2) = o;
}

// ---------------- score MLP via MFMA: scores = lrelu(h2@wm1+bm1)@wm2+bm2 ----------------
__global__ __launch_bounds__(256) void k_score_mfma(
    const float* __restrict__ h2,
    const unsigned short* __restrict__ mh, const unsigned short* __restrict__ ml,
    const float* __restrict__ bm1, const float* __restrict__ wm2, const float* __restrict__ bm2,
    float* __restrict__ scores, int N) {
  int tid = threadIdx.x, l = tid & 63, w = tid >> 6;
  int g = l >> 4, c = l & 15;
  int rbase = blockIdx.x * 64 + w * 16;
  int row = rbase + c;
  int rc = min(row, N - 1);
  const float4* xf = (const float4*)(h2 + (size_t)rc * DIM);

  s16x8 Ah[4], Al[4];
#pragma unroll
  for (int kt = 0; kt < 4; ++kt) {
    float4 p = xf[kt * 8 + g * 2];
    float4 q = xf[kt * 8 + g * 2 + 1];
    s16x8 ah, al;
#define CV(v, j) { unsigned short hb = f2bf(v); ah[j] = (short)hb; al[j] = (short)f2bf((v) - bf2f(hb)); }
    CV(p.x, 0) CV(p.y, 1) CV(p.z, 2) CV(p.w, 3)
    CV(q.x, 4) CV(q.y, 5) CV(q.z, 6) CV(q.w, 7)
#undef CV
    Ah[kt] = ah;
    Al[kt] = al;
  }

  const s16x8* Bh = (const s16x8*)mh;
  const s16x8* Bl = (const s16x8*)ml;
  float v[4] = {0.f, 0.f, 0.f, 0.f};
#pragma unroll
  for (int ct = 0; ct < 4; ++ct) {
    f32x4 acc = {0.f, 0.f, 0.f, 0.f};
    int nb = (ct * 16 + c) * 4;
#pragma unroll
    for (int kt = 0; kt < 4; ++kt) {
      s16x8 bh = Bh[(nb + kt) * 4 + g];
      s16x8 bl = Bl[(nb + kt) * 4 + g];
      acc = __builtin_amdgcn_mfma_f32_16x16x32_bf16(Ah[kt], bh, acc, 0, 0, 0);
      acc = __builtin_amdgcn_mfma_f32_16x16x32_bf16(Ah[kt], bl, acc, 0, 0, 0);
      acc = __builtin_amdgcn_mfma_f32_16x16x32_bf16(Al[kt], bh, acc, 0, 0, 0);
    }
    int col = ct * 16 + c;
    float b = bm1[col], w2 = wm2[col];
#pragma unroll
    for (int r = 0; r < 4; ++r) v[r] += lrelu(acc[r] + b, 0.01f) * w2;
  }
  // reduce across the 16 column-lanes within each row group
#pragma unroll
  for (int r = 0; r < 4; ++r) {
    v[r] += __shfl_xor(v[r], 1, 64);
    v[r] += __shfl_xor(v[r], 2, 64);
    v[r] += __shfl_xor(v[r], 4, 64);
    v[r] += __shfl_xor(v[r], 8, 64);
  }
  if (c == 0) {
    float b2 = bm2[0];
#pragma unroll
    for (int r = 0; r < 4; ++r) {
      int rr = rbase + g * 4 + r;
      if (rr < N) scores[rr] = v[r] + b2;
    }
  }
}

// ---------------- global softmax (no max pass; scores are O(1)) ----------------
__global__ __launch_bounds__(256) void k_expsum(const float* __restrict__ sc, int N,
                                                float* __restrict__ wun, float* __restrict__ psum) {
  __shared__ float red[256];
  int tid = threadIdx.x;
  float s = 0.f;
  for (int i = blockIdx.x * 256 + tid; i < N; i += 256 * gridDim.x) {
    float e = __expf(sc[i]);
    wun[i] = e;
    s += e;
  }
  red[tid] = s; __syncthreads();
  for (int st = 128; st > 0; st >>= 1) { if (tid < st) red[tid] += red[tid + st]; __syncthreads(); }
  if (tid == 0) psum[blockIdx.x] = red[0];
}

__global__ __launch_bounds__(256) void k_gsum(const float* __restrict__ p, int n, float* __restrict__ g) {
  __shared__ float red[256];
  int tid = threadIdx.x;
  red[tid] = (tid < n) ? p[tid] : 0.f; __syncthreads();
  for (int st = 128; st > 0; st >>= 1) { if (tid < st) red[tid] += red[tid + st]; __syncthreads(); }
  if (tid == 0) g[0] = red[0];
}

__global__ __launch_bounds__(128) void k_wagg(const float* __restrict__ wun, const float* __restrict__ h2,
                                              int N, float* __restrict__ agg) {
  int d = threadIdx.x;
  float acc = 0.f;
  for (int n = blockIdx.x; n < N; n += gridDim.x) acc += wun[n] * h2[(size_t)n * DIM + d];
  atomicAdd(&agg[d], acc);
}

// ---------------- final MLP + layernorm (single block, 128 threads) ----------------
__global__ __launch_bounds__(128) void k_final(const float* __restrict__ agg, const float* __restrict__ gZ,
                                               const float* __restrict__ wa1, const float* __restrict__ ba1,
                                               const float* __restrict__ wa2, const float* __restrict__ ba2,
                                               const float* __restrict__ gamma, const float* __restrict__ beta,
                                               float* __restrict__ out) {
  __shared__ float sa[128], sh[64], red[128];
  int t = threadIdx.x;
  float Z = gZ[0];
  sa[t] = agg[t] / Z;
  __syncthreads();
  if (t < 64) {
    float a = 0.f;
    for (int k = 0; k < 128; ++k) a = fmaf(sa[k], wa1[k * 64 + t], a);
    a += ba1[t];
    sh[t] = lrelu(a, 0.01f);
  }
  __syncthreads();
  float z = ba2[t];
  for (int j = 0; j < 64; ++j) z = fmaf(sh[j], wa2[j * 128 + t], z);
  red[t] = z; __syncthreads();
  for (int st = 64; st > 0; st >>= 1) { if (t < st) red[t] += red[t + st]; __syncthreads(); }
  float mu = red[0] / 128.f;
  __syncthreads();
  red[t] = (z - mu) * (z - mu); __syncthreads();
  for (int st = 64; st > 0; st >>= 1) { if (t < st) red[t] += red[t + st]; __syncthreads(); }
  float var = red[0] / 128.f;
  out[t] = gamma[t] * (z - mu) / sqrtf(var + 1e-5f) + beta[t];
}

extern "C" void kernel_launch(void* const* d_in, const int* in_sizes, int n_in,
                              void* d_out, int out_size, void* d_ws, size_t ws_size,
                              hipStream_t stream) {
  const float* feat = (const float*)d_in[0];
  const int* ei = (const int*)d_in[1];
  const float* W1 = (const float*)d_in[2];
  const float* as1 = (const float*)d_in[3];
  const float* ad1 = (const float*)d_in[4];
  const float* b1 = (const float*)d_in[5];
  const float* W2 = (const float*)d_in[6];
  const float* as2 = (const float*)d_in[7];
  const float* ad2 = (const float*)d_in[8];
  const float* b2 = (const float*)d_in[9];
  const float* wm1 = (const float*)d_in[10];
  const float* bm1 = (const float*)d_in[11];
  const float* wm2 = (const float*)d_in[12];
  const float* bm2 = (const float*)d_in[13];
  const float* wa1 = (const float*)d_in[14];
  const float* ba1 = (const float*)d_in[15];
  const float* wa2 = (const float*)d_in[16];
  const float* ba2 = (const float*)d_in[17];
  const float* gamma = (const float*)d_in[18];
  const float* beta = (const float*)d_in[19];
  float* out = (float*)d_out;

  int N = in_sizes[0] / DIM;   // 50000
  int E = in_sizes[1] / 2;     // 600000
  int NB = (N + 255) / 256;

  char* ws = (char*)d_ws;
  size_t off = 0;
  auto alloc = [&](size_t bytes) -> void* {
    void* p = ws + off;
    off = (off + bytes + 255) & ~(size_t)255;
    return p;
  };
  int* cnt = (int*)alloc((size_t)N * 4);
  int* rowptr = (int*)alloc((size_t)(N + 1) * 4);
  int* cursor = (int*)alloc((size_t)N * 4);
  int* colb = (int*)alloc((size_t)(E + N) * 4);
  unsigned short* xhb = (unsigned short*)alloc((size_t)N * DIM * 2);
  float* h1 = (float*)alloc((size_t)N * DIM * 4);
  float* h2 = (float*)alloc((size_t)N * DIM * 4);
  float* asrcb = (float*)alloc((size_t)N * HEADS * 4);
  float* adstb = (float*)alloc((size_t)N * HEADS * 4);
  float* scores = (float*)alloc((size_t)N * 4);
  float* wun = (float*)alloc((size_t)N * 4);
  float* psum = (float*)alloc(256 * 4);
  float* gZ = (float*)alloc(4);
  float* agg = (float*)alloc(DIM * 4);
  int* bsum = (int*)alloc((size_t)NB * 4);
  int* boff = (int*)alloc((size_t)NB * 4);
  unsigned short* wh1 = (unsigned short*)alloc(DIM * DIM * 2);
  unsigned short* wl1 = (unsigned short*)alloc(DIM * DIM * 2);
  unsigned short* sh1 = (unsigned short*)alloc(16 * DIM * 2);
  unsigned short* sl1 = (unsigned short*)alloc(16 * DIM * 2);
  unsigned short* wh2 = (unsigned short*)alloc(DIM * DIM * 2);
  unsigned short* wl2 = (unsigned short*)alloc(DIM * DIM * 2);
  unsigned short* sh2 = (unsigned short*)alloc(16 * DIM * 2);
  unsigned short* sl2 = (unsigned short*)alloc(16 * DIM * 2);
  unsigned short* mh = (unsigned short*)alloc(64 * DIM * 2);
  unsigned short* ml = (unsigned short*)alloc(64 * DIM * 2);

  hipMemsetAsync(cnt, 0, (size_t)N * 4, stream);
  hipMemsetAsync(agg, 0, DIM * 4, stream);

  k_wprep<<<1, 256, 0, stream>>>(W1, as1, ad1, wh1, wl1, sh1, sl1);
  k_wprep<<<1, 256, 0, stream>>>(W2, as2, ad2, wh2, wl2, sh2, sl2);
  k_mlpprep<<<1, 256, 0, stream>>>(wm1, mh, ml);

  k_hist<<<1024, 256, 0, stream>>>(ei, E, N, cnt);
  k_scan_blk<<<NB, 256, 0, stream>>>(cnt, N, cursor, bsum);
  k_scan_top<<<1, 256, 0, stream>>>(bsum, NB, boff, rowptr + N);
  k_scan_fix<<<NB, 256, 0, stream>>>(cursor, boff, N, rowptr);
  k_scatter<<<1024, 256, 0, stream>>>(ei, E, N, cursor, colb);

  int gl = (N + 63) / 64;
  int ga = (N + 3) / 4;
  k_linear_mfma<<<gl, 256, 0, stream>>>(feat, wh1, wl1, sh1, sl1, xhb, asrcb, adstb, N);
  k_gat_agg<<<ga, 256, 0, stream>>>(rowptr, colb, xhb, asrcb, adstb, b1, h1, N);
  k_linear_mfma<<<gl, 256, 0, stream>>>(h1, wh2, wl2, sh2, sl2, xhb, asrcb, adstb, N);
  k_gat_agg<<<ga, 256, 0, stream>>>(rowptr, colb, xhb, asrcb, adstb, b2, h2, N);

  k_score_mfma<<<gl, 256, 0, stream>>>(h2, mh, ml, bm1, wm2, bm2, scores, N);
  k_expsum<<<256, 256, 0, stream>>>(scores, N, wun, psum);
  k_gsum<<<1, 256, 0, stream>>>(psum, 256, gZ);
  k_wagg<<<1024, 128, 0, stream>>>(wun, h2, N, agg);
  k_final<<<1, 128, 0, stream>>>(agg, gZ, wa1, ba1, wa2, ba2, gamma, beta, out);
}

// Round 5
// 354.214 us; speedup vs baseline: 2.0248x; 1.1069x over previous
//
#include <hip/hip_runtime.h>
#include <math.h>

#define DIM 128
#define HEADS 8
#define HD 16
#define CAP 64

typedef __attribute__((ext_vector_type(8))) short s16x8;
typedef __attribute__((ext_vector_type(4))) float f32x4;

__device__ __forceinline__ float lrelu(float x, float s) { return x >= 0.f ? x : s * x; }

__device__ __forceinline__ unsigned short f2bf(float x) {
  unsigned u = __float_as_uint(x);
  return (unsigned short)((u + 0x7FFFu + ((u >> 16) & 1u)) >> 16);
}
__device__ __forceinline__ float bf2f(unsigned short b) {
  return __uint_as_float(((unsigned)b) << 16);
}

// ---------------- CSR build (group edges by destination) ----------------
__global__ void k_hist(const int* __restrict__ ei, int E, int N, int* __restrict__ cnt) {
  int tot = E + N;
  for (int i = blockIdx.x * blockDim.x + threadIdx.x; i < tot; i += gridDim.x * blockDim.x) {
    int d = (i < E) ? ei[E + i] : (i - E);  // self-loops appended
    atomicAdd(&cnt[d], 1);
  }
}

__global__ __launch_bounds__(256) void k_scan_blk(const int* __restrict__ cnt, int n,
                                                  int* __restrict__ excl, int* __restrict__ bsum) {
  __shared__ int wsum[4];
  int tid = threadIdx.x, l = tid & 63, w = tid >> 6;
  int i = blockIdx.x * 256 + tid;
  int v = (i < n) ? cnt[i] : 0;
  int s = v;
#pragma unroll
  for (int off = 1; off < 64; off <<= 1) {
    int t = __shfl_up(s, off, 64);
    if (l >= off) s += t;
  }
  if (l == 63) wsum[w] = s;
  __syncthreads();
  int add = 0;
#pragma unroll
  for (int k = 0; k < 4; ++k) add += (k < w) ? wsum[k] : 0;
  if (i < n) excl[i] = s + add - v;
  if (tid == 255) bsum[blockIdx.x] = s + add;
}

__global__ __launch_bounds__(256) void k_scan_top(const int* __restrict__ bsum, int nb,
                                                  int* __restrict__ boff, int* __restrict__ rowptrN) {
  __shared__ int wsum[4];
  int tid = threadIdx.x, l = tid & 63, w = tid >> 6;
  int v = (tid < nb) ? bsum[tid] : 0;
  int s = v;
#pragma unroll
  for (int off = 1; off < 64; off <<= 1) {
    int t = __shfl_up(s, off, 64);
    if (l >= off) s += t;
  }
  if (l == 63) wsum[w] = s;
  __syncthreads();
  int add = 0;
#pragma unroll
  for (int k = 0; k < 4; ++k) add += (k < w) ? wsum[k] : 0;
  if (tid < nb) boff[tid] = s + add - v;
  if (tid == 255) *rowptrN = s + add;
}

__global__ __launch_bounds__(256) void k_scan_fix(int* __restrict__ cursor, const int* __restrict__ boff,
                                                  int n, int* __restrict__ rowptr) {
  int i = blockIdx.x * 256 + threadIdx.x;
  if (i < n) {
    int r = boff[blockIdx.x] + cursor[i];
    rowptr[i] = r;
    cursor[i] = r;
  }
}

__global__ void k_scatter(const int* __restrict__ ei, int E, int N,
                          int* __restrict__ cursor, int* __restrict__ colb) {
  int tot = E + N;
  for (int i = blockIdx.x * blockDim.x + threadIdx.x; i < tot; i += gridDim.x * blockDim.x) {
    int s, d;
    if (i < E) { s = ei[i]; d = ei[E + i]; } else { s = i - E; d = s; }
    int pos = atomicAdd(&cursor[d], 1);
    colb[pos] = s;
  }
}

// ---------------- weight prep: W^T fragments (split bf16 hi/lo) + alpha-proj cols ----------------
__global__ __launch_bounds__(256) void k_wprep(const float* __restrict__ W,
                                               const float* __restrict__ av_s, const float* __restrict__ av_d,
                                               unsigned short* __restrict__ wh, unsigned short* __restrict__ wl,
                                               unsigned short* __restrict__ sh, unsigned short* __restrict__ sl) {
  int tid = threadIdx.x;
  for (int idx = tid; idx < DIM * DIM; idx += 256) {
    int n = idx >> 7, k = idx & 127;
    float v = W[k * DIM + n];
    unsigned short hb = f2bf(v);
    wh[idx] = hb;
    wl[idx] = f2bf(v - bf2f(hb));
  }
  for (int idx = tid; idx < 16 * DIM; idx += 256) {
    int n = idx >> 7, k = idx & 127;
    float acc = 0.f;
    if (n < 8) {
#pragma unroll
      for (int j = 0; j < 16; ++j) acc += W[k * DIM + n * 16 + j] * av_s[n * 16 + j];
    } else {
      int h = n - 8;
#pragma unroll
      for (int j = 0; j < 16; ++j) acc += W[k * DIM + h * 16 + j] * av_d[h * 16 + j];
    }
    unsigned short hb = f2bf(acc);
    sh[idx] = hb;
    sl[idx] = f2bf(acc - bf2f(hb));
  }
}

// ---------------- score-MLP weight prep: wm1^T split-bf16 fragments ----------------
__global__ __launch_bounds__(256) void k_mlpprep(const float* __restrict__ wm1,
                                                 unsigned short* __restrict__ mh, unsigned short* __restrict__ ml) {
  int tid = threadIdx.x;
  for (int idx = tid; idx < 64 * DIM; idx += 256) {
    int j = idx >> 7, k = idx & 127;   // mh[j][k] = wm1[k][j]
    float v = wm1[k * 64 + j];
    unsigned short hb = f2bf(v);
    mh[idx] = hb;
    ml[idx] = f2bf(v - bf2f(hb));
  }
}

// ---------------- xh = x @ W via split-bf16 MFMA; xh stored as bf16; alphas fused ----------------
__global__ __launch_bounds__(256) void k_linear_mfma(
    const float* __restrict__ x,
    const unsigned short* __restrict__ wh, const unsigned short* __restrict__ wl,
    const unsigned short* __restrict__ sh, const unsigned short* __restrict__ sl,
    unsigned short* __restrict__ xhb, float* __restrict__ asrc, float* __restrict__ adst, int N) {
  int tid = threadIdx.x, l = tid & 63, w = tid >> 6;
  int g = l >> 4, c = l & 15;
  int rbase = blockIdx.x * 64 + w * 16;
  int row = rbase + c;
  int rc = min(row, N - 1);
  const float4* xf = (const float4*)(x + (size_t)rc * DIM);

  s16x8 Ah[4], Al[4];
#pragma unroll
  for (int kt = 0; kt < 4; ++kt) {
    float4 p = xf[kt * 8 + g * 2];
    float4 q = xf[kt * 8 + g * 2 + 1];
    s16x8 ah, al;
#define CV(v, j) { unsigned short hb = f2bf(v); ah[j] = (short)hb; al[j] = (short)f2bf((v) - bf2f(hb)); }
    CV(p.x, 0) CV(p.y, 1) CV(p.z, 2) CV(p.w, 3)
    CV(q.x, 4) CV(q.y, 5) CV(q.z, 6) CV(q.w, 7)
#undef CV
    Ah[kt] = ah;
    Al[kt] = al;
  }

  const s16x8* Bh = (const s16x8*)wh;
  const s16x8* Bl = (const s16x8*)wl;
#pragma unroll
  for (int ct = 0; ct < 8; ++ct) {
    f32x4 acc = {0.f, 0.f, 0.f, 0.f};
    int nb = (ct * 16 + c) * 4;
#pragma unroll
    for (int kt = 0; kt < 4; ++kt) {
      s16x8 bh = Bh[(nb + kt) * 4 + g];
      s16x8 bl = Bl[(nb + kt) * 4 + g];
      acc = __builtin_amdgcn_mfma_f32_16x16x32_bf16(Ah[kt], bh, acc, 0, 0, 0);
      acc = __builtin_amdgcn_mfma_f32_16x16x32_bf16(Ah[kt], bl, acc, 0, 0, 0);
      acc = __builtin_amdgcn_mfma_f32_16x16x32_bf16(Al[kt], bh, acc, 0, 0, 0);
    }
#pragma unroll
    for (int r = 0; r < 4; ++r) {
      int rr = rbase + g * 4 + r;
      if (rr < N) xhb[(size_t)rr * DIM + ct * 16 + c] = f2bf(acc[r]);
    }
  }

  const s16x8* Shp = (const s16x8*)sh;
  const s16x8* Slp = (const s16x8*)sl;
  f32x4 acc = {0.f, 0.f, 0.f, 0.f};
#pragma unroll
  for (int kt = 0; kt < 4; ++kt) {
    s16x8 bh = Shp[(c * 4 + kt) * 4 + g];
    s16x8 bl = Slp[(c * 4 + kt) * 4 + g];
    acc = __builtin_amdgcn_mfma_f32_16x16x32_bf16(Ah[kt], bh, acc, 0, 0, 0);
    acc = __builtin_amdgcn_mfma_f32_16x16x32_bf16(Ah[kt], bl, acc, 0, 0, 0);
    acc = __builtin_amdgcn_mfma_f32_16x16x32_bf16(Al[kt], bh, acc, 0, 0, 0);
  }
#pragma unroll
  for (int r = 0; r < 4; ++r) {
    int rr = rbase + g * 4 + r;
    if (rr < N) {
      if (c < 8) asrc[rr * HEADS + c] = acc[r];
      else adst[rr * HEADS + (c - 8)] = acc[r];
    }
  }
}

// ---------------- GAT aggregation: one wave per destination node ----------------
// colb indices preloaded per-lane then broadcast via shfl -> all gathers independent.
// Pass B: 2 edges/iteration (half-wave split), 8B/lane gathers.
__global__ __launch_bounds__(256) void k_gat_agg(const int* __restrict__ rowptr, const int* __restrict__ colb,
                                                 const unsigned short* __restrict__ xhb,
                                                 const float* __restrict__ asrc, const float* __restrict__ adst,
                                                 const float* __restrict__ bias,
                                                 float* __restrict__ hout, int N) {
  __shared__ float ew[4][CAP][8];
  __shared__ float sdenom[4][8];
  int tid = threadIdx.x, lane = tid & 63, wv = tid >> 6;
  int n = blockIdx.x * 4 + wv;
  int base = 0, deg = 0;
  if (n < N) { base = rowptr[n]; deg = rowptr[n + 1] - base; }
  int cmy = (lane < deg) ? colb[base + lane] : 0;

  int g = lane >> 3, ha = lane & 7;
  float adst_a = (n < N) ? adst[n * HEADS + ha] : 0.f;
  float s = 0.f;
  for (int i = g; i < deg; i += 8) {
    int c = (i < CAP) ? __shfl(cmy, i, 64) : colb[base + i];
    float e = lrelu(asrc[c * HEADS + ha] + adst_a, 0.2f);
    float x = __expf(e);
    if (i < CAP) ew[wv][i][ha] = x;
    s += x;
  }
  s += __shfl_xor(s, 8, 64);
  s += __shfl_xor(s, 16, 64);
  s += __shfl_xor(s, 32, 64);
  if (g == 0) sdenom[wv][ha] = s + 1e-16f;
  __syncthreads();
  if (n >= N) return;

  int half = lane >> 5, q = lane & 31;   // lane covers dims [4q, 4q+4); half-wave picks edge parity
  int h = q >> 2;
  float r = 1.f / sdenom[wv][h];
  float a0 = 0.f, a1 = 0.f, a2 = 0.f, a3 = 0.f;
  for (int i = half; i < deg; i += 2) {
    int c = (i < CAP) ? __shfl(cmy, i, 64) : colb[base + i];
    float wgt;
    if (i < CAP) {
      wgt = ew[wv][i][h] * r;
    } else {  // practically never hit (deg ~ Poisson(12)+1)
      float e = lrelu(asrc[c * HEADS + h] + adst[n * HEADS + h], 0.2f);
      wgt = __expf(e) * r;
    }
    ushort4 u = *(const ushort4*)(xhb + (size_t)c * DIM + q * 4);
    a0 = fmaf(wgt, bf2f(u.x), a0);
    a1 = fmaf(wgt, bf2f(u.y), a1);
    a2 = fmaf(wgt, bf2f(u.z), a2);
    a3 = fmaf(wgt, bf2f(u.w), a3);
  }
  a0 += __shfl_xor(a0, 32, 64);
  a1 += __shfl_xor(a1, 32, 64);
  a2 += __shfl_xor(a2, 32, 64);
  a3 += __shfl_xor(a3, 32, 64);
  if (half == 0) {
    float4 o;
    o.x = lrelu(a0 + bias[q * 4 + 0], 0.01f);
    o.y = lrelu(a1 + bias[q * 4 + 1], 0.01f);
    o.z = lrelu(a2 + bias[q * 4 + 2], 0.01f);
    o.w = lrelu(a3 + bias[q * 4 + 3], 0.01f);
    *(float4*)(hout + (size_t)n * DIM + q * 4) = o;
  }
}

// ---------------- score MLP via MFMA: scores = lrelu(h2@wm1+bm1)@wm2+bm2 ----------------
__global__ __launch_bounds__(256) void k_score_mfma(
    const float* __restrict__ h2,
    const unsigned short* __restrict__ mh, const unsigned short* __restrict__ ml,
    const float* __restrict__ bm1, const float* __restrict__ wm2, const float* __restrict__ bm2,
    float* __restrict__ scores, int N) {
  int tid = threadIdx.x, l = tid & 63, w = tid >> 6;
  int g = l >> 4, c = l & 15;
  int rbase = blockIdx.x * 64 + w * 16;
  int row = rbase + c;
  int rc = min(row, N - 1);
  const float4* xf = (const float4*)(h2 + (size_t)rc * DIM);

  s16x8 Ah[4], Al[4];
#pragma unroll
  for (int kt = 0; kt < 4; ++kt) {
    float4 p = xf[kt * 8 + g * 2];
    float4 q = xf[kt * 8 + g * 2 + 1];
    s16x8 ah, al;
#define CV(v, j) { unsigned short hb = f2bf(v); ah[j] = (short)hb; al[j] = (short)f2bf((v) - bf2f(hb)); }
    CV(p.x, 0) CV(p.y, 1) CV(p.z, 2) CV(p.w, 3)
    CV(q.x, 4) CV(q.y, 5) CV(q.z, 6) CV(q.w, 7)
#undef CV
    Ah[kt] = ah;
    Al[kt] = al;
  }

  const s16x8* Bh = (const s16x8*)mh;
  const s16x8* Bl = (const s16x8*)ml;
  float v[4] = {0.f, 0.f, 0.f, 0.f};
#pragma unroll
  for (int ct = 0; ct < 4; ++ct) {
    f32x4 acc = {0.f, 0.f, 0.f, 0.f};
    int nb = (ct * 16 + c) * 4;
#pragma unroll
    for (int kt = 0; kt < 4; ++kt) {
      s16x8 bh = Bh[(nb + kt) * 4 + g];
      s16x8 bl = Bl[(nb + kt) * 4 + g];
      acc = __builtin_amdgcn_mfma_f32_16x16x32_bf16(Ah[kt], bh, acc, 0, 0, 0);
      acc = __builtin_amdgcn_mfma_f32_16x16x32_bf16(Ah[kt], bl, acc, 0, 0, 0);
      acc = __builtin_amdgcn_mfma_f32_16x16x32_bf16(Al[kt], bh, acc, 0, 0, 0);
    }
    int col = ct * 16 + c;
    float b = bm1[col], w2 = wm2[col];
#pragma unroll
    for (int r = 0; r < 4; ++r) v[r] += lrelu(acc[r] + b, 0.01f) * w2;
  }
#pragma unroll
  for (int r = 0; r < 4; ++r) {
    v[r] += __shfl_xor(v[r], 1, 64);
    v[r] += __shfl_xor(v[r], 2, 64);
    v[r] += __shfl_xor(v[r], 4, 64);
    v[r] += __shfl_xor(v[r], 8, 64);
  }
  if (c == 0) {
    float b2 = bm2[0];
#pragma unroll
    for (int r = 0; r < 4; ++r) {
      int rr = rbase + g * 4 + r;
      if (rr < N) scores[rr] = v[r] + b2;
    }
  }
}

// ---------------- global softmax (no max pass; scores are O(1)) ----------------
__global__ __launch_bounds__(256) void k_expsum(const float* __restrict__ sc, int N,
                                                float* __restrict__ wun, float* __restrict__ psum) {
  __shared__ float red[256];
  int tid = threadIdx.x;
  float s = 0.f;
  for (int i = blockIdx.x * 256 + tid; i < N; i += 256 * gridDim.x) {
    float e = __expf(sc[i]);
    wun[i] = e;
    s += e;
  }
  red[tid] = s; __syncthreads();
  for (int st = 128; st > 0; st >>= 1) { if (tid < st) red[tid] += red[tid + st]; __syncthreads(); }
  if (tid == 0) psum[blockIdx.x] = red[0];
}

__global__ __launch_bounds__(256) void k_gsum(const float* __restrict__ p, int n, float* __restrict__ g) {
  __shared__ float red[256];
  int tid = threadIdx.x;
  red[tid] = (tid < n) ? p[tid] : 0.f; __syncthreads();
  for (int st = 128; st > 0; st >>= 1) { if (tid < st) red[tid] += red[tid + st]; __syncthreads(); }
  if (tid == 0) g[0] = red[0];
}

__global__ __launch_bounds__(128) void k_wagg(const float* __restrict__ wun, const float* __restrict__ h2,
                                              int N, float* __restrict__ agg) {
  int d = threadIdx.x;
  float acc = 0.f;
  for (int n = blockIdx.x; n < N; n += gridDim.x) acc += wun[n] * h2[(size_t)n * DIM + d];
  atomicAdd(&agg[d], acc);
}

// ---------------- final MLP + layernorm (single block, 128 threads) ----------------
__global__ __launch_bounds__(128) void k_final(const float* __restrict__ agg, const float* __restrict__ gZ,
                                               const float* __restrict__ wa1, const float* __restrict__ ba1,
                                               const float* __restrict__ wa2, const float* __restrict__ ba2,
                                               const float* __restrict__ gamma, const float* __restrict__ beta,
                                               float* __restrict__ out) {
  __shared__ float sa[128], sh[64], red[128];
  int t = threadIdx.x;
  float Z = gZ[0];
  sa[t] = agg[t] / Z;
  __syncthreads();
  if (t < 64) {
    float a = 0.f;
    for (int k = 0; k < 128; ++k) a = fmaf(sa[k], wa1[k * 64 + t], a);
    a += ba1[t];
    sh[t] = lrelu(a, 0.01f);
  }
  __syncthreads();
  float z = ba2[t];
  for (int j = 0; j < 64; ++j) z = fmaf(sh[j], wa2[j * 128 + t], z);
  red[t] = z; __syncthreads();
  for (int st = 64; st > 0; st >>= 1) { if (t < st) red[t] += red[t + st]; __syncthreads(); }
  float mu = red[0] / 128.f;
  __syncthreads();
  red[t] = (z - mu) * (z - mu); __syncthreads();
  for (int st = 64; st > 0; st >>= 1) { if (t < st) red[t] += red[t + st]; __syncthreads(); }
  float var = red[0] / 128.f;
  out[t] = gamma[t] * (z - mu) / sqrtf(var + 1e-5f) + beta[t];
}

extern "C" void kernel_launch(void* const* d_in, const int* in_sizes, int n_in,
                              void* d_out, int out_size, void* d_ws, size_t ws_size,
                              hipStream_t stream) {
  const float* feat = (const float*)d_in[0];
  const int* ei = (const int*)d_in[1];
  const float* W1 = (const float*)d_in[2];
  const float* as1 = (const float*)d_in[3];
  const float* ad1 = (const float*)d_in[4];
  const float* b1 = (const float*)d_in[5];
  const float* W2 = (const float*)d_in[6];
  const float* as2 = (const float*)d_in[7];
  const float* ad2 = (const float*)d_in[8];
  const float* b2 = (const float*)d_in[9];
  const float* wm1 = (const float*)d_in[10];
  const float* bm1 = (const float*)d_in[11];
  const float* wm2 = (const float*)d_in[12];
  const float* bm2 = (const float*)d_in[13];
  const float* wa1 = (const float*)d_in[14];
  const float* ba1 = (const float*)d_in[15];
  const float* wa2 = (const float*)d_in[16];
  const float* ba2 = (const float*)d_in[17];
  const float* gamma = (const float*)d_in[18];
  const float* beta = (const float*)d_in[19];
  float* out = (float*)d_out;

  int N = in_sizes[0] / DIM;   // 50000
  int E = in_sizes[1] / 2;     // 600000
  int NB = (N + 255) / 256;

  char* ws = (char*)d_ws;
  size_t off = 0;
  auto alloc = [&](size_t bytes) -> void* {
    void* p = ws + off;
    off = (off + bytes + 255) & ~(size_t)255;
    return p;
  };
  int* cnt = (int*)alloc((size_t)N * 4);
  int* rowptr = (int*)alloc((size_t)(N + 1) * 4);
  int* cursor = (int*)alloc((size_t)N * 4);
  int* colb = (int*)alloc((size_t)(E + N) * 4);
  unsigned short* xhb = (unsigned short*)alloc((size_t)N * DIM * 2);
  float* h1 = (float*)alloc((size_t)N * DIM * 4);
  float* h2 = (float*)alloc((size_t)N * DIM * 4);
  float* asrcb = (float*)alloc((size_t)N * HEADS * 4);
  float* adstb = (float*)alloc((size_t)N * HEADS * 4);
  float* scores = (float*)alloc((size_t)N * 4);
  float* wun = (float*)alloc((size_t)N * 4);
  float* psum = (float*)alloc(256 * 4);
  float* gZ = (float*)alloc(4);
  float* agg = (float*)alloc(DIM * 4);
  int* bsum = (int*)alloc((size_t)NB * 4);
  int* boff = (int*)alloc((size_t)NB * 4);
  unsigned short* wh1 = (unsigned short*)alloc(DIM * DIM * 2);
  unsigned short* wl1 = (unsigned short*)alloc(DIM * DIM * 2);
  unsigned short* sh1 = (unsigned short*)alloc(16 * DIM * 2);
  unsigned short* sl1 = (unsigned short*)alloc(16 * DIM * 2);
  unsigned short* wh2 = (unsigned short*)alloc(DIM * DIM * 2);
  unsigned short* wl2 = (unsigned short*)alloc(DIM * DIM * 2);
  unsigned short* sh2 = (unsigned short*)alloc(16 * DIM * 2);
  unsigned short* sl2 = (unsigned short*)alloc(16 * DIM * 2);
  unsigned short* mh = (unsigned short*)alloc(64 * DIM * 2);
  unsigned short* ml = (unsigned short*)alloc(64 * DIM * 2);

  hipMemsetAsync(cnt, 0, (size_t)N * 4, stream);
  hipMemsetAsync(agg, 0, DIM * 4, stream);

  k_wprep<<<1, 256, 0, stream>>>(W1, as1, ad1, wh1, wl1, sh1, sl1);
  k_wprep<<<1, 256, 0, stream>>>(W2, as2, ad2, wh2, wl2, sh2, sl2);
  k_mlpprep<<<1, 256, 0, stream>>>(wm1, mh, ml);

  k_hist<<<1024, 256, 0, stream>>>(ei, E, N, cnt);
  k_scan_blk<<<NB, 256, 0, stream>>>(cnt, N, cursor, bsum);
  k_scan_top<<<1, 256, 0, stream>>>(bsum, NB, boff, rowptr + N);
  k_scan_fix<<<NB, 256, 0, stream>>>(cursor, boff, N, rowptr);
  k_scatter<<<1024, 256, 0, stream>>>(ei, E, N, cursor, colb);

  int gl = (N + 63) / 64;
  int ga = (N + 3) / 4;
  k_linear_mfma<<<gl, 256, 0, stream>>>(feat, wh1, wl1, sh1, sl1, xhb, asrcb, adstb, N);
  k_gat_agg<<<ga, 256, 0, stream>>>(rowptr, colb, xhb, asrcb, adstb, b1, h1, N);
  k_linear_mfma<<<gl, 256, 0, stream>>>(h1, wh2, wl2, sh2, sl2, xhb, asrcb, adstb, N);
  k_gat_agg<<<ga, 256, 0, stream>>>(rowptr, colb, xhb, asrcb, adstb, b2, h2, N);

  k_score_mfma<<<gl, 256, 0, stream>>>(h2, mh, ml, bm1, wm2, bm2, scores, N);
  k_expsum<<<256, 256, 0, stream>>>(scores, N, wun, psum);
  k_gsum<<<1, 256, 0, stream>>>(psum, 256, gZ);
  k_wagg<<<1024, 128, 0, stream>>>(wun, h2, N, agg);
  k_final<<<1, 128, 0, stream>>>(agg, gZ, wa1, ba1, wa2, ba2, gamma, beta, out);
}